// Round 1
// baseline (457.279 us; speedup 1.0000x reference)
//
#include <hip/hip_runtime.h>
#include <hip/hip_bf16.h>
#include <stdint.h>

// ---------------------------------------------------------------------------
// ImageAttention (SAM-style, decomposed rel-pos) on MI355X / gfx950.
// All heavy math in split-bf16 (hi+lo) MFMA: C = Ah*Bh + Ah*Bl + Al*Bh,
// fp32 accumulate -> ~1e-4 accuracy at bf16-MFMA speed. P@V is plain bf16
// (softmax weights average out rounding noise).
//
// Pipeline:
//   split(x,wqkv,wproj) -> G1 qkv split-GEMM (epilogue scatters Q/K/V,
//   folds scale*log2e into K) -> V transpose -> rel_h/rel_w einsums (x log2e)
//   -> flash attention (exp2 online softmax) -> split(O) -> G2 proj GEMM.
// ---------------------------------------------------------------------------

typedef unsigned short u16;
typedef unsigned int   u32;
typedef __attribute__((ext_vector_type(8))) short s8v;   // 8 x bf16 (4 VGPR)
typedef __attribute__((ext_vector_type(4))) float f4v;   // MFMA acc
typedef __attribute__((ext_vector_type(4))) unsigned short us4;
typedef __attribute__((ext_vector_type(8))) unsigned short us8;

#define DEVI static __device__ __forceinline__

constexpr int   NTOK   = 4096;
constexpr int   DM     = 768;
constexpr float LOG2E_F = 1.4426950408889634f;
constexpr float KSCALE  = 0.18033688011112042f;   // (1/8) * log2(e)

DEVI u16 f2bf(float x){
  u32 u = __builtin_bit_cast(u32, x);
  u32 r = (u + 0x7FFFu + ((u >> 16) & 1u)) >> 16;
  return (u16)r;
}
DEVI float bf2f(u16 h){
  u32 u = ((u32)h) << 16;
  return __builtin_bit_cast(float, u);
}

typedef const __attribute__((address_space(1))) u32* gp1;
typedef __attribute__((address_space(3))) u32* lp3;
DEVI void gload_lds16(const void* g, void* l){
  __builtin_amdgcn_global_load_lds((gp1)g, (lp3)l, 16, 0, 0);
}

DEVI f4v MFMA16(s8v a, s8v b, f4v c){
  return __builtin_amdgcn_mfma_f32_16x16x32_bf16(a, b, c, 0, 0, 0);
}

// ------------------------------------------------------------------ split ---
__global__ void k_split(const float* __restrict__ in, u16* __restrict__ hi,
                        u16* __restrict__ lo, int n4){
  int i = blockIdx.x * blockDim.x + threadIdx.x;
  int stride = gridDim.x * blockDim.x;
  for (; i < n4; i += stride){
    f4v v = ((const f4v*)in)[i];
    us4 h, l;
#pragma unroll
    for (int j = 0; j < 4; ++j){
      u16 hb = f2bf(v[j]);
      h[j] = hb;
      l[j] = f2bf(v[j] - bf2f(hb));
    }
    ((us4*)hi)[i] = h;
    ((us4*)lo)[i] = l;
  }
}

// ------------------------------------------------------------- split GEMM ---
// C[M,N] = (Ah+Al)[M,K] @ (Bh+Bl)[N,K]^T, 128x128 tile, BK=32, 4 waves.
// LDS tiles are [128 rows][64B]; paired-row swizzle:
//   phys(row,cb) = (row>>1)*128 + (((row&1)*64 + cb) ^ (((row>>1)&7)<<4))
// -> ds_read_b128 of 16 rows at fixed cb is 2-way (free).
// EPI==1: qkv scatter epilogue; EPI==2: plain f32 store (+bias).
template<int EPI>
__global__ __launch_bounds__(256)
void k_gemm(const u16* __restrict__ Ah, const u16* __restrict__ Al,
            const u16* __restrict__ Bh, const u16* __restrict__ Bl,
            const float* __restrict__ bias, int K,
            u16* __restrict__ Qh, u16* __restrict__ Ql,
            u16* __restrict__ Kh, u16* __restrict__ Kl,
            float* __restrict__ Vf, float* __restrict__ Cout)
{
  __shared__ __align__(16) unsigned char sm[32768]; // Ah|Al|Bh|Bl  8KB each
  const int t = threadIdx.x;
  const int lane = t & 63, wid = t >> 6;
  const int l15 = lane & 15, g = lane >> 4;
  const int wr = wid >> 1, wc = wid & 1;
  const int m0 = blockIdx.y * 128, n0 = blockIdx.x * 128;

  // staging: invert swizzle -> per-thread (row, cb) per 4KB chunk
  const char* aGh[2]; const char* aGl[2]; const char* bGh[2]; const char* bGl[2];
#pragma unroll
  for (int ch = 0; ch < 2; ++ch){
    int p = ch * 4096 + t * 16;
    int pair = p >> 7, w = p & 127;
    int u = w ^ ((pair & 7) << 4);
    int row = 2 * pair + (u >> 6);
    int cb  = u & 63;
    aGh[ch] = (const char*)Ah + (size_t)(m0 + row) * K * 2 + cb;
    aGl[ch] = (const char*)Al + (size_t)(m0 + row) * K * 2 + cb;
    bGh[ch] = (const char*)Bh + (size_t)(n0 + row) * K * 2 + cb;
    bGl[ch] = (const char*)Bl + (size_t)(n0 + row) * K * 2 + cb;
  }
  // LDS read bases (fixed across K-steps): +mi*1024 / +ni*1024, +8192 for lo
  const int axor = ((l15 & 1) * 64 + g * 16) ^ (((l15 >> 1) & 7) << 4);
  const int abase = (wr * 32 + (l15 >> 1)) * 128 + axor;
  const int bbase = 16384 + (wc * 32 + (l15 >> 1)) * 128 + axor;

  f4v acc[4][4] = {};
  const int KSTEPS = K >> 5;
  for (int kt = 0; kt < KSTEPS; ++kt){
    __syncthreads();
#pragma unroll
    for (int ch = 0; ch < 2; ++ch){
      gload_lds16(aGh[ch], sm + 0     + ch*4096 + wid*1024);
      gload_lds16(aGl[ch], sm + 8192  + ch*4096 + wid*1024);
      gload_lds16(bGh[ch], sm + 16384 + ch*4096 + wid*1024);
      gload_lds16(bGl[ch], sm + 24576 + ch*4096 + wid*1024);
      aGh[ch] += 64; aGl[ch] += 64; bGh[ch] += 64; bGl[ch] += 64;
    }
    __syncthreads();
    s8v af[4][2];
#pragma unroll
    for (int mi = 0; mi < 4; ++mi){
      af[mi][0] = *(const s8v*)(sm + abase + mi*1024);
      af[mi][1] = *(const s8v*)(sm + abase + mi*1024 + 8192);
    }
#pragma unroll
    for (int ni = 0; ni < 4; ++ni){
      s8v bh = *(const s8v*)(sm + bbase + ni*1024);
      s8v bl = *(const s8v*)(sm + bbase + ni*1024 + 8192);
#pragma unroll
      for (int mi = 0; mi < 4; ++mi){
        acc[mi][ni] = MFMA16(af[mi][0], bh, acc[mi][ni]);
        acc[mi][ni] = MFMA16(af[mi][0], bl, acc[mi][ni]);
        acc[mi][ni] = MFMA16(af[mi][1], bh, acc[mi][ni]);
      }
    }
  }

  // epilogue: C row = m0+wr*64+mi*16+4g+r ; col = n0+wc*64+ni*16+l15
  if (EPI == 2){
#pragma unroll
    for (int ni = 0; ni < 4; ++ni){
      int col = n0 + wc*64 + ni*16 + l15;
      float bq = bias[col];
#pragma unroll
      for (int mi = 0; mi < 4; ++mi){
        int rw0 = m0 + wr*64 + mi*16 + g*4;
#pragma unroll
        for (int r = 0; r < 4; ++r)
          Cout[(size_t)(rw0 + r) * DM + col] = acc[mi][ni][r] + bq;
      }
    }
  } else {
#pragma unroll
    for (int ni = 0; ni < 4; ++ni){
      int colb = n0 + wc*64 + ni*16;        // tile never straddles 768/64 edges
      float bq = bias[colb + l15];
      int which = colb / DM;
      int rem   = colb % DM;
      int head  = rem >> 6;
      int c     = (rem & 63) + l15;
#pragma unroll
      for (int mi = 0; mi < 4; ++mi){
        int n = m0 + wr*64 + mi*16 + g*4;
#pragma unroll
        for (int r = 0; r < 4; ++r){
          float v = acc[mi][ni][r] + bq;
          size_t idx = ((size_t)head * NTOK + (n + r)) * 64 + c;
          if (which == 0){
            u16 hb = f2bf(v);
            Qh[idx] = hb; Ql[idx] = f2bf(v - bf2f(hb));
          } else if (which == 1){
            float v2 = v * KSCALE;            // fold softmax scale * log2(e)
            u16 hb = f2bf(v2);
            Kh[idx] = hb; Kl[idx] = f2bf(v2 - bf2f(hb));
          } else {
            Vf[idx] = v;
          }
        }
      }
    }
  }
}

// ------------------------------------------------------------ V transpose ---
// Vf [h][n][c] f32  ->  Vth [h][c][n] bf16 (hi only; PV is plain-bf16)
__global__ void k_vtrans(const float* __restrict__ Vf, u16* __restrict__ Vth){
  __shared__ float tile[64][65];
  int h = blockIdx.y, nt = blockIdx.x;
  int t = threadIdx.x;
  {
    int r = t >> 2, c0 = (t & 3) * 16;
    const float* src = Vf + ((size_t)h * NTOK + nt*64 + r) * 64 + c0;
#pragma unroll
    for (int j = 0; j < 4; ++j){
      f4v v = *(const f4v*)(src + j*4);
      tile[r][c0+j*4+0] = v[0]; tile[r][c0+j*4+1] = v[1];
      tile[r][c0+j*4+2] = v[2]; tile[r][c0+j*4+3] = v[3];
    }
  }
  __syncthreads();
  {
    int c = t >> 2, b = (t & 3) * 16;
    us8 o0, o1;
#pragma unroll
    for (int i = 0; i < 16; ++i){
      u16 bv = f2bf(tile[b + i][c]);
      if (i < 8) o0[i] = bv; else o1[i-8] = bv;
    }
    u16* dst = Vth + ((size_t)h * 64 + c) * NTOK + nt*64 + b;
    *(us8*)(dst)     = o0;
    *(us8*)(dst + 8) = o1;
  }
}

// --------------------------------------------------------- rel-pos einsums ---
// Rh[h][qh*64+qw][kh] = log2e * sum_c q * rel_pos_h[qh-kh+63][c]
__global__ void k_relh(const u16* __restrict__ Qh, const u16* __restrict__ Ql,
                       const float* __restrict__ rp, float* __restrict__ R){
  __shared__ float qs[64][68];
  __shared__ float rs[64][68];
  int h = blockIdx.y, qh = blockIdx.x;
  int t = threadIdx.x;
  {
    int r = t >> 2, c0 = (t & 3) * 16;
    size_t qb = ((size_t)h * NTOK + qh*64 + r) * 64 + c0;
#pragma unroll
    for (int j = 0; j < 2; ++j){
      us8 vh = *(const us8*)(Qh + qb + j*8);
      us8 vl = *(const us8*)(Ql + qb + j*8);
#pragma unroll
      for (int e = 0; e < 8; ++e)
        qs[r][c0 + j*8 + e] = bf2f(vh[e]) + bf2f(vl[e]);
    }
    const float* pr = rp + (size_t)(qh - r + 63) * 64 + c0;
#pragma unroll
    for (int j = 0; j < 4; ++j){
      f4v v = *(const f4v*)(pr + j*4);
      rs[r][c0+j*4+0]=v[0]; rs[r][c0+j*4+1]=v[1];
      rs[r][c0+j*4+2]=v[2]; rs[r][c0+j*4+3]=v[3];
    }
  }
  __syncthreads();
  int qw = t >> 2, k0 = t & 3;
  float acc[16] = {};
  for (int c = 0; c < 64; c += 4){
    f4v qv = *(const f4v*)(&qs[qw][c]);
#pragma unroll
    for (int i = 0; i < 16; ++i){
      f4v rv = *(const f4v*)(&rs[k0 + 4*i][c]);
      acc[i] += qv[0]*rv[0] + qv[1]*rv[1] + qv[2]*rv[2] + qv[3]*rv[3];
    }
  }
  float* o = R + ((size_t)h * NTOK + qh*64 + qw) * 64;
#pragma unroll
  for (int i = 0; i < 16; ++i) o[k0 + 4*i] = acc[i] * LOG2E_F;
}

// Rw[h][qh*64+qw][kw] = log2e * sum_c q * rel_pos_w[qw-kw+63][c]
__global__ void k_relw(const u16* __restrict__ Qh, const u16* __restrict__ Ql,
                       const float* __restrict__ rp, float* __restrict__ R){
  __shared__ float qs[64][68];   // [qh][c]
  __shared__ float rs[64][68];   // [kw][c]
  int h = blockIdx.y, qw = blockIdx.x;
  int t = threadIdx.x;
  {
    int r = t >> 2, c0 = (t & 3) * 16;
    size_t qb = ((size_t)h * NTOK + r*64 + qw) * 64 + c0;
#pragma unroll
    for (int j = 0; j < 2; ++j){
      us8 vh = *(const us8*)(Qh + qb + j*8);
      us8 vl = *(const us8*)(Ql + qb + j*8);
#pragma unroll
      for (int e = 0; e < 8; ++e)
        qs[r][c0 + j*8 + e] = bf2f(vh[e]) + bf2f(vl[e]);
    }
    const float* pr = rp + (size_t)(qw - r + 63) * 64 + c0;
#pragma unroll
    for (int j = 0; j < 4; ++j){
      f4v v = *(const f4v*)(pr + j*4);
      rs[r][c0+j*4+0]=v[0]; rs[r][c0+j*4+1]=v[1];
      rs[r][c0+j*4+2]=v[2]; rs[r][c0+j*4+3]=v[3];
    }
  }
  __syncthreads();
  int qh = t >> 2, k0 = t & 3;
  float acc[16] = {};
  for (int c = 0; c < 64; c += 4){
    f4v qv = *(const f4v*)(&qs[qh][c]);
#pragma unroll
    for (int i = 0; i < 16; ++i){
      f4v rv = *(const f4v*)(&rs[k0 + 4*i][c]);
      acc[i] += qv[0]*rv[0] + qv[1]*rv[1] + qv[2]*rv[2] + qv[3]*rv[3];
    }
  }
  float* o = R + ((size_t)h * NTOK + qh*64 + qw) * 64;
#pragma unroll
  for (int i = 0; i < 16; ++i) o[k0 + 4*i] = acc[i] * LOG2E_F;
}

// --------------------------------------------------------- flash attention ---
// grid (64 q-tiles, 12 heads), 4 waves x 16 q-rows. KV tile = 64.
// QK^T split-bf16 (3 terms), exp2 online softmax, P@V plain bf16.
// LDS: Kh[64][128B]@0, Kl@8192, Vt[64][128B]@16384 (xor ((row&7)<<4)),
//      P per wave @24576+wid*2304, 16 rows, stride 144B (padded, no xor).
__global__ __launch_bounds__(256)
void k_attn(const u16* __restrict__ Qh, const u16* __restrict__ Ql,
            const u16* __restrict__ Kh, const u16* __restrict__ Kl,
            const u16* __restrict__ Vth,
            const float* __restrict__ Rh, const float* __restrict__ Rw,
            float* __restrict__ O)
{
  __shared__ __align__(16) unsigned char sm[33792];
  const int t = threadIdx.x;
  const int lane = t & 63, wid = t >> 6;
  const int l15 = lane & 15, g = lane >> 4;
  const int h = blockIdx.y;
  const int qrow0 = blockIdx.x * 64 + wid * 16;

  // staging pointers (xor-swizzled source, linear LDS dest)
  const char* kGh[2]; const char* kGl[2]; const char* vG[2];
#pragma unroll
  for (int ch = 0; ch < 2; ++ch){
    int p = ch * 4096 + t * 16;
    int row = p >> 7;
    int cb  = (p & 127) ^ ((row & 7) << 4);
    kGh[ch] = (const char*)Kh + ((size_t)h * NTOK + row) * 128 + cb;
    kGl[ch] = (const char*)Kl + ((size_t)h * NTOK + row) * 128 + cb;
    vG[ch]  = (const char*)Vth + ((size_t)h * 64 + row) * (NTOK*2) + cb;
  }

  // Q fragments (held in registers for whole kernel)
  const size_t qoff = ((size_t)h * NTOK + qrow0 + l15) * 64 + g * 8;
  s8v qh0 = *(const s8v*)(Qh + qoff);
  s8v qh1 = *(const s8v*)(Qh + qoff + 32);
  s8v ql0 = *(const s8v*)(Ql + qoff);
  s8v ql1 = *(const s8v*)(Ql + qoff + 32);

  // LDS read bases. xor uses row&7 == l15&7; kk=32 needs its own base
  // (xor and +64 don't commute when xor bit6 is set).
  const int xr  = (l15 & 7) << 4;
  const int kb0 = l15 * 128 + ((g * 16)      ^ xr);
  const int kb1 = l15 * 128 + ((g * 16 + 64) ^ xr);
  const int vb0 = 16384 + kb0;
  const int vb1 = 16384 + kb1;
  const int pwb = 24576 + wid * 2304 + (4 * g) * 144 + 2 * l15;
  const int prb = 24576 + wid * 2304 + l15 * 144 + g * 16;

  // rel_w values are iteration-invariant -> hoist
  float rwv[4][4];
#pragma unroll
  for (int r = 0; r < 4; ++r){
    const float* p = Rw + ((size_t)h * NTOK + qrow0 + 4*g + r) * 64 + l15;
#pragma unroll
    for (int q = 0; q < 4; ++q) rwv[q][r] = p[q*16];
  }
  const float* rhp[4];
#pragma unroll
  for (int r = 0; r < 4; ++r)
    rhp[r] = Rh + ((size_t)h * NTOK + qrow0 + 4*g + r) * 64;

  f4v o[4] = {};
  float m2[4], ls[4];
#pragma unroll
  for (int r = 0; r < 4; ++r){ m2[r] = -1.0e30f; ls[r] = 0.f; }

  for (int it = 0; it < 64; ++it){
    __syncthreads();
#pragma unroll
    for (int ch = 0; ch < 2; ++ch){
      gload_lds16(kGh[ch], sm + 0     + ch*4096 + wid*1024);
      gload_lds16(kGl[ch], sm + 8192  + ch*4096 + wid*1024);
      gload_lds16(vG[ch],  sm + 16384 + ch*4096 + wid*1024);
      kGh[ch] += 8192; kGl[ch] += 8192; vG[ch] += 128;
    }
    __syncthreads();

    float rhv[4];
#pragma unroll
    for (int r = 0; r < 4; ++r) rhv[r] = rhp[r][it];

    // S = Q K^T (split: hh, hl, lh), quarter q covers k-cols 16q..16q+15
    f4v s[4];
#pragma unroll
    for (int q = 0; q < 4; ++q){
      s8v kh_0 = *(const s8v*)(sm + kb0 + q*2048);
      s8v kh_1 = *(const s8v*)(sm + kb1 + q*2048);
      s8v kl_0 = *(const s8v*)(sm + kb0 + q*2048 + 8192);
      s8v kl_1 = *(const s8v*)(sm + kb1 + q*2048 + 8192);
      f4v a = {};
      a = MFMA16(qh0, kh_0, a);
      a = MFMA16(qh1, kh_1, a);
      a = MFMA16(qh0, kl_0, a);
      a = MFMA16(qh1, kl_1, a);
      a = MFMA16(ql0, kh_0, a);
      a = MFMA16(ql1, kh_1, a);
      s[q] = a;
    }
    // bias + row max (16 lanes share a q-row: shfl_xor 1,2,4,8)
    float vm[4];
#pragma unroll
    for (int r = 0; r < 4; ++r){
#pragma unroll
      for (int q = 0; q < 4; ++q) s[q][r] += rhv[r] + rwv[q][r];
      vm[r] = fmaxf(fmaxf(s[0][r], s[1][r]), fmaxf(s[2][r], s[3][r]));
    }
#pragma unroll
    for (int mk = 1; mk <= 8; mk <<= 1){
#pragma unroll
      for (int r = 0; r < 4; ++r) vm[r] = fmaxf(vm[r], __shfl_xor(vm[r], mk, 64));
    }
    float fr[4];
#pragma unroll
    for (int r = 0; r < 4; ++r){
      float mn = fmaxf(m2[r], vm[r]);
      fr[r] = exp2f(m2[r] - mn);
      m2[r] = mn;
    }
    float ps[4] = {0.f, 0.f, 0.f, 0.f};
#pragma unroll
    for (int q = 0; q < 4; ++q){
#pragma unroll
      for (int r = 0; r < 4; ++r){
        float p = exp2f(s[q][r] - m2[r]);
        s[q][r] = p;
        ps[r] += p;
      }
    }
#pragma unroll
    for (int mk = 1; mk <= 8; mk <<= 1){
#pragma unroll
      for (int r = 0; r < 4; ++r) ps[r] += __shfl_xor(ps[r], mk, 64);
    }
#pragma unroll
    for (int r = 0; r < 4; ++r) ls[r] = ls[r] * fr[r] + ps[r];

    // P -> LDS (bf16, per-wave region, padded stride -> no barrier needed)
#pragma unroll
    for (int r = 0; r < 4; ++r){
#pragma unroll
      for (int q = 0; q < 4; ++q)
        *(u16*)(sm + pwb + r*144 + q*32) = f2bf(s[q][r]);
    }
    // rescale O
#pragma unroll
    for (int dt = 0; dt < 4; ++dt){
#pragma unroll
      for (int r = 0; r < 4; ++r) o[dt][r] *= fr[r];
    }
    // O += P @ V
    s8v pa0 = *(const s8v*)(sm + prb);
    s8v pa1 = *(const s8v*)(sm + prb + 64);
#pragma unroll
    for (int dt = 0; dt < 4; ++dt){
      s8v v0 = *(const s8v*)(sm + vb0 + dt*2048);
      s8v v1 = *(const s8v*)(sm + vb1 + dt*2048);
      o[dt] = MFMA16(pa0, v0, o[dt]);
      o[dt] = MFMA16(pa1, v1, o[dt]);
    }
  }

  float inv[4];
#pragma unroll
  for (int r = 0; r < 4; ++r) inv[r] = 1.0f / ls[r];
#pragma unroll
  for (int dt = 0; dt < 4; ++dt){
#pragma unroll
    for (int r = 0; r < 4; ++r){
      int qrow = qrow0 + 4*g + r;
      O[(size_t)qrow * DM + h*64 + dt*16 + l15] = o[dt][r] * inv[r];
    }
  }
}

// ------------------------------------------------------------------- host ---
extern "C" void kernel_launch(void* const* d_in, const int* in_sizes, int n_in,
                              void* d_out, int out_size, void* d_ws, size_t ws_size,
                              hipStream_t stream){
  (void)in_sizes; (void)n_in; (void)out_size; (void)ws_size;
  const float* x      = (const float*)d_in[0];
  const float* w_qkv  = (const float*)d_in[1];
  const float* b_qkv  = (const float*)d_in[2];
  const float* w_proj = (const float*)d_in[3];
  const float* b_proj = (const float*)d_in[4];
  const float* rph    = (const float*)d_in[5];
  const float* rpw    = (const float*)d_in[6];
  float* out = (float*)d_out;

  char* w = (char*)d_ws;
  size_t off = 0;
  auto nxt = [&](size_t b) -> char* {
    char* p = w + off; off += (b + 255) & ~(size_t)255; return p;
  };
  u16*   Xh  = (u16*)  nxt((size_t)NTOK*DM*2);        // 6.29 MB
  u16*   Xl  = (u16*)  nxt((size_t)NTOK*DM*2);
  u16*   Wqh = (u16*)  nxt((size_t)3*DM*DM*2);
  u16*   Wql = (u16*)  nxt((size_t)3*DM*DM*2);
  u16*   Wph = (u16*)  nxt((size_t)DM*DM*2);
  u16*   Wpl = (u16*)  nxt((size_t)DM*DM*2);
  u16*   Qh  = (u16*)  nxt((size_t)NTOK*DM*2);
  u16*   Ql  = (u16*)  nxt((size_t)NTOK*DM*2);
  u16*   Kh  = (u16*)  nxt((size_t)NTOK*DM*2);
  u16*   Kl  = (u16*)  nxt((size_t)NTOK*DM*2);
  float* Vf  = (float*)nxt((size_t)NTOK*DM*4);        // also reused as Of
  u16*   Vth = (u16*)  nxt((size_t)NTOK*DM*2);
  float* Rh  = (float*)nxt((size_t)12*NTOK*64*4);
  float* Rw  = (float*)nxt((size_t)12*NTOK*64*4);
  float* Of  = Vf;                                    // Vf dead after k_vtrans
  u16*   Oh  = Xh;                                    // X dead after G1
  u16*   Ol  = Xl;

  k_split<<<dim3(3072), dim3(256), 0, stream>>>(x,      Xh,  Xl,  NTOK*DM/4);
  k_split<<<dim3(1728), dim3(256), 0, stream>>>(w_qkv,  Wqh, Wql, 3*DM*DM/4);
  k_split<<<dim3(576),  dim3(256), 0, stream>>>(w_proj, Wph, Wpl, DM*DM/4);

  k_gemm<1><<<dim3(18, 32), dim3(256), 0, stream>>>(
      Xh, Xl, Wqh, Wql, b_qkv, DM, Qh, Ql, Kh, Kl, Vf, nullptr);

  k_vtrans<<<dim3(64, 12), dim3(256), 0, stream>>>(Vf, Vth);
  k_relh  <<<dim3(64, 12), dim3(256), 0, stream>>>(Qh, Ql, rph, Rh);
  k_relw  <<<dim3(64, 12), dim3(256), 0, stream>>>(Qh, Ql, rpw, Rw);

  k_attn<<<dim3(64, 12), dim3(256), 0, stream>>>(Qh, Ql, Kh, Kl, Vth, Rh, Rw, Of);

  k_split<<<dim3(3072), dim3(256), 0, stream>>>(Of, Oh, Ol, NTOK*DM/4);

  k_gemm<2><<<dim3(6, 32), dim3(256), 0, stream>>>(
      Oh, Ol, Wph, Wpl, b_proj, DM,
      nullptr, nullptr, nullptr, nullptr, nullptr, out);
}

// Round 3
// 377.849 us; speedup vs baseline: 1.2102x; 1.2102x over previous
//
#include <hip/hip_runtime.h>
#include <hip/hip_bf16.h>
#include <stdint.h>

// ---------------------------------------------------------------------------
// ImageAttention (SAM-style, decomposed rel-pos) on MI355X / gfx950.
// Split-bf16 (hi+lo) MFMA for QKV/proj GEMMs and QK^T; P@V plain bf16.
// R2 (resubmit; R2 bench never ran): swapped-operand attention
// (mfma(K,Q) / mfma(V,P)) -> per-lane scalar softmax state, 2-shuffle
// reduces, cvt_pk+b64 P round trip, vector epilogue with fused O hi/lo split.
// ---------------------------------------------------------------------------

typedef unsigned short u16;
typedef unsigned int   u32;
typedef __attribute__((ext_vector_type(8))) short s8v;   // 8 x bf16 (4 VGPR)
typedef __attribute__((ext_vector_type(4))) float f4v;   // MFMA acc
typedef __attribute__((ext_vector_type(4))) unsigned short us4;
typedef __attribute__((ext_vector_type(8))) unsigned short us8;
typedef __attribute__((ext_vector_type(2))) unsigned int u32x2;

#define DEVI static __device__ __forceinline__

constexpr int   NTOK   = 4096;
constexpr int   DM     = 768;
constexpr float LOG2E_F = 1.4426950408889634f;
constexpr float KSCALE  = 0.18033688011112042f;   // (1/8) * log2(e)

#if __has_builtin(__builtin_amdgcn_exp2f)
#define EXP2(x) __builtin_amdgcn_exp2f(x)
#else
#define EXP2(x) exp2f(x)
#endif

DEVI u16 f2bf(float x){
  u32 u = __builtin_bit_cast(u32, x);
  u32 r = (u + 0x7FFFu + ((u >> 16) & 1u)) >> 16;
  return (u16)r;
}
DEVI float bf2f(u16 h){
  u32 u = ((u32)h) << 16;
  return __builtin_bit_cast(float, u);
}
DEVI u32 cvtpk(float lo, float hi){   // dst.lo16 = bf16(lo), dst.hi16 = bf16(hi)
  u32 r;
  asm("v_cvt_pk_bf16_f32 %0, %1, %2" : "=v"(r) : "v"(lo), "v"(hi));
  return r;
}

typedef const __attribute__((address_space(1))) u32* gp1;
typedef __attribute__((address_space(3))) u32* lp3;
DEVI void gload_lds16(const void* g, void* l){
  __builtin_amdgcn_global_load_lds((gp1)g, (lp3)l, 16, 0, 0);
}

DEVI f4v MFMA16(s8v a, s8v b, f4v c){
  return __builtin_amdgcn_mfma_f32_16x16x32_bf16(a, b, c, 0, 0, 0);
}

// ------------------------------------------------------------------ split ---
__global__ void k_split(const float* __restrict__ in, u16* __restrict__ hi,
                        u16* __restrict__ lo, int n4){
  int i = blockIdx.x * blockDim.x + threadIdx.x;
  int stride = gridDim.x * blockDim.x;
  for (; i < n4; i += stride){
    f4v v = ((const f4v*)in)[i];
    us4 h, l;
#pragma unroll
    for (int j = 0; j < 4; ++j){
      u16 hb = f2bf(v[j]);
      h[j] = hb;
      l[j] = f2bf(v[j] - bf2f(hb));
    }
    ((us4*)hi)[i] = h;
    ((us4*)lo)[i] = l;
  }
}

// ------------------------------------------------------------- split GEMM ---
// C[M,N] = (Ah+Al)[M,K] @ (Bh+Bl)[N,K]^T, 128x128 tile, BK=32, 4 waves.
// LDS tiles are [128 rows][64B]; paired-row swizzle:
//   phys(row,cb) = (row>>1)*128 + (((row&1)*64 + cb) ^ (((row>>1)&7)<<4))
// EPI==1: qkv scatter epilogue; EPI==2: plain f32 store (+bias).
template<int EPI>
__global__ __launch_bounds__(256)
void k_gemm(const u16* __restrict__ Ah, const u16* __restrict__ Al,
            const u16* __restrict__ Bh, const u16* __restrict__ Bl,
            const float* __restrict__ bias, int K,
            u16* __restrict__ Qh, u16* __restrict__ Ql,
            u16* __restrict__ Kh, u16* __restrict__ Kl,
            float* __restrict__ Vf, float* __restrict__ Cout)
{
  __shared__ __align__(16) unsigned char sm[32768]; // Ah|Al|Bh|Bl  8KB each
  const int t = threadIdx.x;
  const int lane = t & 63, wid = t >> 6;
  const int l15 = lane & 15, g = lane >> 4;
  const int wr = wid >> 1, wc = wid & 1;
  const int m0 = blockIdx.y * 128, n0 = blockIdx.x * 128;

  const char* aGh[2]; const char* aGl[2]; const char* bGh[2]; const char* bGl[2];
#pragma unroll
  for (int ch = 0; ch < 2; ++ch){
    int p = ch * 4096 + t * 16;
    int pair = p >> 7, w = p & 127;
    int u = w ^ ((pair & 7) << 4);
    int row = 2 * pair + (u >> 6);
    int cb  = u & 63;
    aGh[ch] = (const char*)Ah + (size_t)(m0 + row) * K * 2 + cb;
    aGl[ch] = (const char*)Al + (size_t)(m0 + row) * K * 2 + cb;
    bGh[ch] = (const char*)Bh + (size_t)(n0 + row) * K * 2 + cb;
    bGl[ch] = (const char*)Bl + (size_t)(n0 + row) * K * 2 + cb;
  }
  const int axor = ((l15 & 1) * 64 + g * 16) ^ (((l15 >> 1) & 7) << 4);
  const int abase = (wr * 32 + (l15 >> 1)) * 128 + axor;
  const int bbase = 16384 + (wc * 32 + (l15 >> 1)) * 128 + axor;

  f4v acc[4][4] = {};
  const int KSTEPS = K >> 5;
  for (int kt = 0; kt < KSTEPS; ++kt){
    __syncthreads();
#pragma unroll
    for (int ch = 0; ch < 2; ++ch){
      gload_lds16(aGh[ch], sm + 0     + ch*4096 + wid*1024);
      gload_lds16(aGl[ch], sm + 8192  + ch*4096 + wid*1024);
      gload_lds16(bGh[ch], sm + 16384 + ch*4096 + wid*1024);
      gload_lds16(bGl[ch], sm + 24576 + ch*4096 + wid*1024);
      aGh[ch] += 64; aGl[ch] += 64; bGh[ch] += 64; bGl[ch] += 64;
    }
    __syncthreads();
    s8v af[4][2];
#pragma unroll
    for (int mi = 0; mi < 4; ++mi){
      af[mi][0] = *(const s8v*)(sm + abase + mi*1024);
      af[mi][1] = *(const s8v*)(sm + abase + mi*1024 + 8192);
    }
#pragma unroll
    for (int ni = 0; ni < 4; ++ni){
      s8v bh = *(const s8v*)(sm + bbase + ni*1024);
      s8v bl = *(const s8v*)(sm + bbase + ni*1024 + 8192);
#pragma unroll
      for (int mi = 0; mi < 4; ++mi){
        acc[mi][ni] = MFMA16(af[mi][0], bh, acc[mi][ni]);
        acc[mi][ni] = MFMA16(af[mi][0], bl, acc[mi][ni]);
        acc[mi][ni] = MFMA16(af[mi][1], bh, acc[mi][ni]);
      }
    }
  }

  if (EPI == 2){
#pragma unroll
    for (int ni = 0; ni < 4; ++ni){
      int col = n0 + wc*64 + ni*16 + l15;
      float bq = bias[col];
#pragma unroll
      for (int mi = 0; mi < 4; ++mi){
        int rw0 = m0 + wr*64 + mi*16 + g*4;
#pragma unroll
        for (int r = 0; r < 4; ++r)
          Cout[(size_t)(rw0 + r) * DM + col] = acc[mi][ni][r] + bq;
      }
    }
  } else {
#pragma unroll
    for (int ni = 0; ni < 4; ++ni){
      int colb = n0 + wc*64 + ni*16;        // tile never straddles 768/64 edges
      float bq = bias[colb + l15];
      int which = colb / DM;
      int rem   = colb % DM;
      int head  = rem >> 6;
      int c     = (rem & 63) + l15;
#pragma unroll
      for (int mi = 0; mi < 4; ++mi){
        int n = m0 + wr*64 + mi*16 + g*4;
#pragma unroll
        for (int r = 0; r < 4; ++r){
          float v = acc[mi][ni][r] + bq;
          size_t idx = ((size_t)head * NTOK + (n + r)) * 64 + c;
          if (which == 0){
            u16 hb = f2bf(v);
            Qh[idx] = hb; Ql[idx] = f2bf(v - bf2f(hb));
          } else if (which == 1){
            float v2 = v * KSCALE;            // fold softmax scale * log2(e)
            u16 hb = f2bf(v2);
            Kh[idx] = hb; Kl[idx] = f2bf(v2 - bf2f(hb));
          } else {
            Vf[idx] = v;
          }
        }
      }
    }
  }
}

// ------------------------------------------------------------ V transpose ---
// Vf [h][n][c] f32  ->  Vth [h][c][n] bf16 (hi only; PV is plain-bf16)
__global__ void k_vtrans(const float* __restrict__ Vf, u16* __restrict__ Vth){
  __shared__ float tile[64][65];
  int h = blockIdx.y, nt = blockIdx.x;
  int t = threadIdx.x;
  {
    int r = t >> 2, c0 = (t & 3) * 16;
    const float* src = Vf + ((size_t)h * NTOK + nt*64 + r) * 64 + c0;
#pragma unroll
    for (int j = 0; j < 4; ++j){
      f4v v = *(const f4v*)(src + j*4);
      tile[r][c0+j*4+0] = v[0]; tile[r][c0+j*4+1] = v[1];
      tile[r][c0+j*4+2] = v[2]; tile[r][c0+j*4+3] = v[3];
    }
  }
  __syncthreads();
  {
    int c = t >> 2, b = (t & 3) * 16;
    us8 o0, o1;
#pragma unroll
    for (int i = 0; i < 16; ++i){
      u16 bv = f2bf(tile[b + i][c]);
      if (i < 8) o0[i] = bv; else o1[i-8] = bv;
    }
    u16* dst = Vth + ((size_t)h * 64 + c) * NTOK + nt*64 + b;
    *(us8*)(dst)     = o0;
    *(us8*)(dst + 8) = o1;
  }
}

// --------------------------------------------------------- rel-pos einsums ---
__global__ void k_relh(const u16* __restrict__ Qh, const u16* __restrict__ Ql,
                       const float* __restrict__ rp, float* __restrict__ R){
  __shared__ float qs[64][68];
  __shared__ float rs[64][68];
  int h = blockIdx.y, qh = blockIdx.x;
  int t = threadIdx.x;
  {
    int r = t >> 2, c0 = (t & 3) * 16;
    size_t qb = ((size_t)h * NTOK + qh*64 + r) * 64 + c0;
#pragma unroll
    for (int j = 0; j < 2; ++j){
      us8 vh = *(const us8*)(Qh + qb + j*8);
      us8 vl = *(const us8*)(Ql + qb + j*8);
#pragma unroll
      for (int e = 0; e < 8; ++e)
        qs[r][c0 + j*8 + e] = bf2f(vh[e]) + bf2f(vl[e]);
    }
    const float* pr = rp + (size_t)(qh - r + 63) * 64 + c0;
#pragma unroll
    for (int j = 0; j < 4; ++j){
      f4v v = *(const f4v*)(pr + j*4);
      rs[r][c0+j*4+0]=v[0]; rs[r][c0+j*4+1]=v[1];
      rs[r][c0+j*4+2]=v[2]; rs[r][c0+j*4+3]=v[3];
    }
  }
  __syncthreads();
  int qw = t >> 2, k0 = t & 3;
  float acc[16] = {};
  for (int c = 0; c < 64; c += 4){
    f4v qv = *(const f4v*)(&qs[qw][c]);
#pragma unroll
    for (int i = 0; i < 16; ++i){
      f4v rv = *(const f4v*)(&rs[k0 + 4*i][c]);
      acc[i] += qv[0]*rv[0] + qv[1]*rv[1] + qv[2]*rv[2] + qv[3]*rv[3];
    }
  }
  float* o = R + ((size_t)h * NTOK + qh*64 + qw) * 64;
#pragma unroll
  for (int i = 0; i < 16; ++i) o[k0 + 4*i] = acc[i] * LOG2E_F;
}

__global__ void k_relw(const u16* __restrict__ Qh, const u16* __restrict__ Ql,
                       const float* __restrict__ rp, float* __restrict__ R){
  __shared__ float qs[64][68];   // [qh][c]
  __shared__ float rs[64][68];   // [kw][c]
  int h = blockIdx.y, qw = blockIdx.x;
  int t = threadIdx.x;
  {
    int r = t >> 2, c0 = (t & 3) * 16;
    size_t qb = ((size_t)h * NTOK + r*64 + qw) * 64 + c0;
#pragma unroll
    for (int j = 0; j < 2; ++j){
      us8 vh = *(const us8*)(Qh + qb + j*8);
      us8 vl = *(const us8*)(Ql + qb + j*8);
#pragma unroll
      for (int e = 0; e < 8; ++e)
        qs[r][c0 + j*8 + e] = bf2f(vh[e]) + bf2f(vl[e]);
    }
    const float* pr = rp + (size_t)(qw - r + 63) * 64 + c0;
#pragma unroll
    for (int j = 0; j < 4; ++j){
      f4v v = *(const f4v*)(pr + j*4);
      rs[r][c0+j*4+0]=v[0]; rs[r][c0+j*4+1]=v[1];
      rs[r][c0+j*4+2]=v[2]; rs[r][c0+j*4+3]=v[3];
    }
  }
  __syncthreads();
  int qh = t >> 2, k0 = t & 3;
  float acc[16] = {};
  for (int c = 0; c < 64; c += 4){
    f4v qv = *(const f4v*)(&qs[qh][c]);
#pragma unroll
    for (int i = 0; i < 16; ++i){
      f4v rv = *(const f4v*)(&rs[k0 + 4*i][c]);
      acc[i] += qv[0]*rv[0] + qv[1]*rv[1] + qv[2]*rv[2] + qv[3]*rv[3];
    }
  }
  float* o = R + ((size_t)h * NTOK + qh*64 + qw) * 64;
#pragma unroll
  for (int i = 0; i < 16; ++i) o[k0 + 4*i] = acc[i] * LOG2E_F;
}

// --------------------------------------------------------- flash attention ---
// grid (64 q-tiles, 12 heads), 4 waves x 16 q-rows. KV tile = 64.
// SWAPPED operands: S^T = mfma(K, Q) so each lane owns ONE q-row (l15):
// softmax state is scalar/lane, reduces are 2 shuffles (masks 16,32).
// P packed with v_cvt_pk_bf16_f32, stored as 4 ds_write_b64 into a padded
// stride-144 per-wave buffer; PV = mfma(Vt, P) -> O accum is q-row-local.
// Epilogue fuses the O hi/lo bf16 split (no separate k_split pass).
// LDS: Kh[64][128B]@0, Kl@8192, Vt[64][128B]@16384 (xor ((row&7)<<4)),
//      P per wave @24576+wid*2304 : [16 q][64 k] bf16, row stride 144B.
__global__ __launch_bounds__(256)
void k_attn(const u16* __restrict__ Qh, const u16* __restrict__ Ql,
            const u16* __restrict__ Kh, const u16* __restrict__ Kl,
            const u16* __restrict__ Vth,
            const float* __restrict__ Rh, const float* __restrict__ Rw,
            u16* __restrict__ Oh, u16* __restrict__ Ol)
{
  __shared__ __align__(16) unsigned char sm[33792];
  const int t = threadIdx.x;
  const int lane = t & 63, wid = t >> 6;
  const int l15 = lane & 15, g = lane >> 4;
  const int h = blockIdx.y;
  const int qrow0 = blockIdx.x * 64 + wid * 16;

  // staging pointers (xor-swizzled source, linear LDS dest)
  const char* kGh[2]; const char* kGl[2]; const char* vG[2];
#pragma unroll
  for (int ch = 0; ch < 2; ++ch){
    int p = ch * 4096 + t * 16;
    int row = p >> 7;
    int cb  = (p & 127) ^ ((row & 7) << 4);
    kGh[ch] = (const char*)Kh + ((size_t)h * NTOK + row) * 128 + cb;
    kGl[ch] = (const char*)Kl + ((size_t)h * NTOK + row) * 128 + cb;
    vG[ch]  = (const char*)Vth + ((size_t)h * 64 + row) * (NTOK*2) + cb;
  }

  // Q fragments (B-operand; row = q = l15, d = g*8+e), held all kernel
  const size_t qoff = ((size_t)h * NTOK + qrow0 + l15) * 64 + g * 8;
  s8v qh0 = *(const s8v*)(Qh + qoff);
  s8v qh1 = *(const s8v*)(Qh + qoff + 32);
  s8v ql0 = *(const s8v*)(Ql + qoff);
  s8v ql1 = *(const s8v*)(Ql + qoff + 32);

  // K/V LDS read bases (A-operand; row = 16t + l15, d-bytes 16g / +64)
  const int xr  = (l15 & 7) << 4;
  const int kb0 = l15 * 128 + ((g * 16)      ^ xr);
  const int kb1 = l15 * 128 + ((g * 16 + 64) ^ xr);
  const int vb0 = 16384 + kb0;
  const int vb1 = 16384 + kb1;
  // P buffer: row l15, stride 144
  const int pbase = 24576 + wid * 2304 + l15 * 144;

  // rel_w hoist: rwv[t][r] = Rw[h][q][16t + 4g + r]  (iteration-invariant)
  const float* rwp = Rw + ((size_t)h * NTOK + qrow0 + l15) * 64 + 4*g;
  f4v rwv[4];
#pragma unroll
  for (int tt = 0; tt < 4; ++tt) rwv[tt] = *(const f4v*)(rwp + 16*tt);
  const float* rhp = Rh + ((size_t)h * NTOK + qrow0 + l15) * 64;

  f4v o[4] = {};
  float m2 = -1.0e30f, ls = 0.f;

  for (int it = 0; it < 64; ++it){
    __syncthreads();
#pragma unroll
    for (int ch = 0; ch < 2; ++ch){
      gload_lds16(kGh[ch], sm + 0     + ch*4096 + wid*1024);
      gload_lds16(kGl[ch], sm + 8192  + ch*4096 + wid*1024);
      gload_lds16(vG[ch],  sm + 16384 + ch*4096 + wid*1024);
      kGh[ch] += 8192; kGl[ch] += 8192; vG[ch] += 128;
    }
    __syncthreads();

    const float rhv = rhp[it];   // rel_h: scalar per lane per iteration

    // S^T = K Q^T (split: hh, hl, lh). s[t][r] = S[k=16t+4g+r][q=l15]
    f4v s[4];
#pragma unroll
    for (int tt = 0; tt < 4; ++tt){
      s8v kh_0 = *(const s8v*)(sm + kb0 + tt*2048);
      s8v kh_1 = *(const s8v*)(sm + kb1 + tt*2048);
      s8v kl_0 = *(const s8v*)(sm + kb0 + tt*2048 + 8192);
      s8v kl_1 = *(const s8v*)(sm + kb1 + tt*2048 + 8192);
      f4v a = {};
      a = MFMA16(kh_0, qh0, a);
      a = MFMA16(kh_1, qh1, a);
      a = MFMA16(kl_0, qh0, a);
      a = MFMA16(kl_1, qh1, a);
      a = MFMA16(kh_0, ql0, a);
      a = MFMA16(kh_1, ql1, a);
      s[tt] = a;
    }
    // bias + row max (all 16 values belong to q-row l15)
    float pm = -1.0e30f;
#pragma unroll
    for (int tt = 0; tt < 4; ++tt){
#pragma unroll
      for (int r = 0; r < 4; ++r){
        s[tt][r] += rhv + rwv[tt][r];
        pm = fmaxf(pm, s[tt][r]);
      }
    }
    pm = fmaxf(pm, __shfl_xor(pm, 16, 64));
    pm = fmaxf(pm, __shfl_xor(pm, 32, 64));
    const float mn = fmaxf(m2, pm);
    const float fr = EXP2(m2 - mn);
    m2 = mn;
    float ps = 0.f;
#pragma unroll
    for (int tt = 0; tt < 4; ++tt){
#pragma unroll
      for (int r = 0; r < 4; ++r){
        float p = EXP2(s[tt][r] - m2);
        s[tt][r] = p;
        ps += p;
      }
    }
    ps += __shfl_xor(ps, 16, 64);
    ps += __shfl_xor(ps, 32, 64);
    ls = ls * fr + ps;

    // P -> LDS: chunk t covers k = 16t+4g .. +3 (bytes 32t + 8g)
#pragma unroll
    for (int tt = 0; tt < 4; ++tt){
      u32x2 w2;
      w2[0] = cvtpk(s[tt][0], s[tt][1]);
      w2[1] = cvtpk(s[tt][2], s[tt][3]);
      *(u32x2*)(sm + pbase + 8*g + 32*tt) = w2;
    }
    // rescale O (scalar factor: accumulator is q-row-local)
#pragma unroll
    for (int dt = 0; dt < 4; ++dt){
#pragma unroll
      for (int r = 0; r < 4; ++r) o[dt][r] *= fr;
    }
    // O^T += Vt @ P^T : B-frag = P[q=l15][k = 32kh2 + 8g + e]
    s8v pa0 = *(const s8v*)(sm + pbase + 16*g);
    s8v pa1 = *(const s8v*)(sm + pbase + 16*g + 64);
#pragma unroll
    for (int dt = 0; dt < 4; ++dt){
      s8v v0 = *(const s8v*)(sm + vb0 + dt*2048);
      s8v v1 = *(const s8v*)(sm + vb1 + dt*2048);
      o[dt] = MFMA16(v0, pa0, o[dt]);
      o[dt] = MFMA16(v1, pa1, o[dt]);
    }
  }

  // epilogue: o[dt][r] = O[q = qrow0+l15][d = 16dt + 4g + r]; fused hi/lo split
  const float inv = 1.0f / ls;
  const size_t obase = (size_t)(qrow0 + l15) * DM + h*64 + 4*g;
#pragma unroll
  for (int dt = 0; dt < 4; ++dt){
    us4 hv, lv;
#pragma unroll
    for (int r = 0; r < 4; ++r){
      float v = o[dt][r] * inv;
      u16 hb = f2bf(v);
      hv[r] = hb;
      lv[r] = f2bf(v - bf2f(hb));
    }
    *(us4*)(Oh + obase + 16*dt) = hv;
    *(us4*)(Ol + obase + 16*dt) = lv;
  }
}

// ------------------------------------------------------------------- host ---
extern "C" void kernel_launch(void* const* d_in, const int* in_sizes, int n_in,
                              void* d_out, int out_size, void* d_ws, size_t ws_size,
                              hipStream_t stream){
  (void)in_sizes; (void)n_in; (void)out_size; (void)ws_size;
  const float* x      = (const float*)d_in[0];
  const float* w_qkv  = (const float*)d_in[1];
  const float* b_qkv  = (const float*)d_in[2];
  const float* w_proj = (const float*)d_in[3];
  const float* b_proj = (const float*)d_in[4];
  const float* rph    = (const float*)d_in[5];
  const float* rpw    = (const float*)d_in[6];
  float* out = (float*)d_out;

  char* w = (char*)d_ws;
  size_t off = 0;
  auto nxt = [&](size_t b) -> char* {
    char* p = w + off; off += (b + 255) & ~(size_t)255; return p;
  };
  u16*   Xh  = (u16*)  nxt((size_t)NTOK*DM*2);
  u16*   Xl  = (u16*)  nxt((size_t)NTOK*DM*2);
  u16*   Wqh = (u16*)  nxt((size_t)3*DM*DM*2);
  u16*   Wql = (u16*)  nxt((size_t)3*DM*DM*2);
  u16*   Wph = (u16*)  nxt((size_t)DM*DM*2);
  u16*   Wpl = (u16*)  nxt((size_t)DM*DM*2);
  u16*   Qh  = (u16*)  nxt((size_t)NTOK*DM*2);
  u16*   Ql  = (u16*)  nxt((size_t)NTOK*DM*2);
  u16*   Kh  = (u16*)  nxt((size_t)NTOK*DM*2);
  u16*   Kl  = (u16*)  nxt((size_t)NTOK*DM*2);
  float* Vf  = (float*)nxt((size_t)NTOK*DM*4);
  u16*   Vth = (u16*)  nxt((size_t)NTOK*DM*2);
  float* Rh  = (float*)nxt((size_t)12*NTOK*64*4);
  float* Rw  = (float*)nxt((size_t)12*NTOK*64*4);
  u16*   Oh  = Xh;                                    // X dead after G1
  u16*   Ol  = Xl;

  k_split<<<dim3(3072), dim3(256), 0, stream>>>(x,      Xh,  Xl,  NTOK*DM/4);
  k_split<<<dim3(1728), dim3(256), 0, stream>>>(w_qkv,  Wqh, Wql, 3*DM*DM/4);
  k_split<<<dim3(576),  dim3(256), 0, stream>>>(w_proj, Wph, Wpl, DM*DM/4);

  k_gemm<1><<<dim3(18, 32), dim3(256), 0, stream>>>(
      Xh, Xl, Wqh, Wql, b_qkv, DM, Qh, Ql, Kh, Kl, Vf, nullptr);

  k_vtrans<<<dim3(64, 12), dim3(256), 0, stream>>>(Vf, Vth);
  k_relh  <<<dim3(64, 12), dim3(256), 0, stream>>>(Qh, Ql, rph, Rh);
  k_relw  <<<dim3(64, 12), dim3(256), 0, stream>>>(Qh, Ql, rpw, Rw);

  k_attn<<<dim3(64, 12), dim3(256), 0, stream>>>(Qh, Ql, Kh, Kl, Vth, Rh, Rw, Oh, Ol);

  k_gemm<2><<<dim3(6, 32), dim3(256), 0, stream>>>(
      Oh, Ol, Wph, Wpl, b_proj, DM,
      nullptr, nullptr, nullptr, nullptr, nullptr, out);
}

// Round 6
// 373.519 us; speedup vs baseline: 1.2242x; 1.0116x over previous
//
#include <hip/hip_runtime.h>
#include <hip/hip_bf16.h>
#include <stdint.h>

// ---------------------------------------------------------------------------
// ImageAttention (SAM-style, decomposed rel-pos) on MI355X / gfx950.
// Split-bf16 (hi+lo) MFMA for QKV/proj GEMMs and QK^T; P@V plain bf16.
// R4 (2nd resubmit; bench never ran R4/R5): 2-phase double-buffered pipelines
// (T3/T4-lite) in k_attn and k_gemm:
//   STAGE(next) -> counted s_waitcnt vmcnt(N) (never 0 in loop) -> s_barrier
//   -> compute -> s_barrier.  Rh staged to LDS (padded stride 272) so the
//   inner loop has NO global loads that would break counted vmcnt.
//   T5 setprio(1) around MFMA clusters.
// ---------------------------------------------------------------------------

typedef unsigned short u16;
typedef unsigned int   u32;
typedef __attribute__((ext_vector_type(8))) short s8v;   // 8 x bf16 (4 VGPR)
typedef __attribute__((ext_vector_type(4))) float f4v;   // MFMA acc
typedef __attribute__((ext_vector_type(4))) unsigned short us4;
typedef __attribute__((ext_vector_type(8))) unsigned short us8;
typedef __attribute__((ext_vector_type(2))) unsigned int u32x2;

#define DEVI static __device__ __forceinline__

constexpr int   NTOK   = 4096;
constexpr int   DM     = 768;
constexpr float LOG2E_F = 1.4426950408889634f;
constexpr float KSCALE  = 0.18033688011112042f;   // (1/8) * log2(e)

#if __has_builtin(__builtin_amdgcn_exp2f)
#define EXP2(x) __builtin_amdgcn_exp2f(x)
#else
#define EXP2(x) exp2f(x)
#endif

DEVI u16 f2bf(float x){
  u32 u = __builtin_bit_cast(u32, x);
  u32 r = (u + 0x7FFFu + ((u >> 16) & 1u)) >> 16;
  return (u16)r;
}
DEVI float bf2f(u16 h){
  u32 u = ((u32)h) << 16;
  return __builtin_bit_cast(float, u);
}
DEVI u32 cvtpk(float lo, float hi){   // dst.lo16 = bf16(lo), dst.hi16 = bf16(hi)
  u32 r;
  asm("v_cvt_pk_bf16_f32 %0, %1, %2" : "=v"(r) : "v"(lo), "v"(hi));
  return r;
}

typedef const __attribute__((address_space(1))) u32* gp1;
typedef __attribute__((address_space(3))) u32* lp3;
DEVI void gload_lds16(const void* g, void* l){
  __builtin_amdgcn_global_load_lds((gp1)g, (lp3)l, 16, 0, 0);
}

DEVI f4v MFMA16(s8v a, s8v b, f4v c){
  return __builtin_amdgcn_mfma_f32_16x16x32_bf16(a, b, c, 0, 0, 0);
}

// raw barrier with compiler fences (no vmcnt/lgkm drain!)
DEVI void hard_barrier(){
  __builtin_amdgcn_sched_barrier(0);
  asm volatile("" ::: "memory");
  __builtin_amdgcn_s_barrier();
  asm volatile("" ::: "memory");
  __builtin_amdgcn_sched_barrier(0);
}

// ------------------------------------------------------------------ split ---
__global__ void k_split(const float* __restrict__ in, u16* __restrict__ hi,
                        u16* __restrict__ lo, int n4){
  int i = blockIdx.x * blockDim.x + threadIdx.x;
  int stride = gridDim.x * blockDim.x;
  for (; i < n4; i += stride){
    f4v v = ((const f4v*)in)[i];
    us4 h, l;
#pragma unroll
    for (int j = 0; j < 4; ++j){
      u16 hb = f2bf(v[j]);
      h[j] = hb;
      l[j] = f2bf(v[j] - bf2f(hb));
    }
    ((us4*)hi)[i] = h;
    ((us4*)lo)[i] = l;
  }
}

// ------------------------------------------------------------- split GEMM ---
// C[M,N] = (Ah+Al)[M,K] @ (Bh+Bl)[N,K]^T, 128x128 tile, BK=32, 4 waves.
// Double-buffered LDS (2 x 32KB), 2-phase pipeline, counted vmcnt(8).
// Per-buffer layout [Ah|Al|Bh|Bl] 8KB each; paired-row swizzle:
//   phys(row,cb) = (row>>1)*128 + (((row&1)*64 + cb) ^ (((row>>1)&7)<<4))
// EPI==1: qkv scatter epilogue; EPI==2: plain f32 store (+bias).
template<int EPI>
__global__ __launch_bounds__(256)
void k_gemm(const u16* __restrict__ Ah, const u16* __restrict__ Al,
            const u16* __restrict__ Bh, const u16* __restrict__ Bl,
            const float* __restrict__ bias, int K,
            u16* __restrict__ Qh, u16* __restrict__ Ql,
            u16* __restrict__ Kh, u16* __restrict__ Kl,
            float* __restrict__ Vf, float* __restrict__ Cout)
{
  __shared__ __align__(16) unsigned char sm[65536]; // 2 x (Ah|Al|Bh|Bl 8KB)
  const int t = threadIdx.x;
  const int lane = t & 63, wid = t >> 6;
  const int l15 = lane & 15, g = lane >> 4;
  const int wr = wid >> 1, wc = wid & 1;
  const int m0 = blockIdx.y * 128, n0 = blockIdx.x * 128;

  const char* aGh[2]; const char* aGl[2]; const char* bGh[2]; const char* bGl[2];
#pragma unroll
  for (int ch = 0; ch < 2; ++ch){
    int p = ch * 4096 + t * 16;
    int pair = p >> 7, w = p & 127;
    int u = w ^ ((pair & 7) << 4);
    int row = 2 * pair + (u >> 6);
    int cb  = u & 63;
    aGh[ch] = (const char*)Ah + (size_t)(m0 + row) * K * 2 + cb;
    aGl[ch] = (const char*)Al + (size_t)(m0 + row) * K * 2 + cb;
    bGh[ch] = (const char*)Bh + (size_t)(n0 + row) * K * 2 + cb;
    bGl[ch] = (const char*)Bl + (size_t)(n0 + row) * K * 2 + cb;
  }
  const int axor = ((l15 & 1) * 64 + g * 16) ^ (((l15 >> 1) & 7) << 4);
  const int abase = (wr * 32 + (l15 >> 1)) * 128 + axor;
  const int bbase = 16384 + (wc * 32 + (l15 >> 1)) * 128 + axor;

  // prologue: stage K-step 0 into buffer 0
#pragma unroll
  for (int ch = 0; ch < 2; ++ch){
    gload_lds16(aGh[ch], sm + 0     + ch*4096 + wid*1024);
    gload_lds16(aGl[ch], sm + 8192  + ch*4096 + wid*1024);
    gload_lds16(bGh[ch], sm + 16384 + ch*4096 + wid*1024);
    gload_lds16(bGl[ch], sm + 24576 + ch*4096 + wid*1024);
    aGh[ch] += 64; aGl[ch] += 64; bGh[ch] += 64; bGl[ch] += 64;
  }

  f4v acc[4][4] = {};
  const int KSTEPS = K >> 5;
  for (int kt = 0; kt < KSTEPS; ++kt){
    const int bb = (kt & 1) * 32768;
    if (kt + 1 < KSTEPS){
      const int nb = ((kt + 1) & 1) * 32768;
#pragma unroll
      for (int ch = 0; ch < 2; ++ch){
        gload_lds16(aGh[ch], sm + nb + 0     + ch*4096 + wid*1024);
        gload_lds16(aGl[ch], sm + nb + 8192  + ch*4096 + wid*1024);
        gload_lds16(bGh[ch], sm + nb + 16384 + ch*4096 + wid*1024);
        gload_lds16(bGl[ch], sm + nb + 24576 + ch*4096 + wid*1024);
        aGh[ch] += 64; aGl[ch] += 64; bGh[ch] += 64; bGl[ch] += 64;
      }
      asm volatile("s_waitcnt vmcnt(8)" ::: "memory");   // step kt landed
    } else {
      asm volatile("s_waitcnt vmcnt(0)" ::: "memory");
    }
    hard_barrier();

    s8v af[4][2];
#pragma unroll
    for (int mi = 0; mi < 4; ++mi){
      af[mi][0] = *(const s8v*)(sm + bb + abase + mi*1024);
      af[mi][1] = *(const s8v*)(sm + bb + abase + mi*1024 + 8192);
    }
    __builtin_amdgcn_s_setprio(1);
#pragma unroll
    for (int ni = 0; ni < 4; ++ni){
      s8v bh = *(const s8v*)(sm + bb + bbase + ni*1024);
      s8v bl = *(const s8v*)(sm + bb + bbase + ni*1024 + 8192);
#pragma unroll
      for (int mi = 0; mi < 4; ++mi){
        acc[mi][ni] = MFMA16(af[mi][0], bh, acc[mi][ni]);
        acc[mi][ni] = MFMA16(af[mi][0], bl, acc[mi][ni]);
        acc[mi][ni] = MFMA16(af[mi][1], bh, acc[mi][ni]);
      }
    }
    __builtin_amdgcn_s_setprio(0);
    hard_barrier();   // protect buf[kt&1] before restage at kt+2
  }

  if (EPI == 2){
#pragma unroll
    for (int ni = 0; ni < 4; ++ni){
      int col = n0 + wc*64 + ni*16 + l15;
      float bq = bias[col];
#pragma unroll
      for (int mi = 0; mi < 4; ++mi){
        int rw0 = m0 + wr*64 + mi*16 + g*4;
#pragma unroll
        for (int r = 0; r < 4; ++r)
          Cout[(size_t)(rw0 + r) * DM + col] = acc[mi][ni][r] + bq;
      }
    }
  } else {
#pragma unroll
    for (int ni = 0; ni < 4; ++ni){
      int colb = n0 + wc*64 + ni*16;        // tile never straddles 768/64 edges
      float bq = bias[colb + l15];
      int which = colb / DM;
      int rem   = colb % DM;
      int head  = rem >> 6;
      int c     = (rem & 63) + l15;
#pragma unroll
      for (int mi = 0; mi < 4; ++mi){
        int n = m0 + wr*64 + mi*16 + g*4;
#pragma unroll
        for (int r = 0; r < 4; ++r){
          float v = acc[mi][ni][r] + bq;
          size_t idx = ((size_t)head * NTOK + (n + r)) * 64 + c;
          if (which == 0){
            u16 hb = f2bf(v);
            Qh[idx] = hb; Ql[idx] = f2bf(v - bf2f(hb));
          } else if (which == 1){
            float v2 = v * KSCALE;            // fold softmax scale * log2(e)
            u16 hb = f2bf(v2);
            Kh[idx] = hb; Kl[idx] = f2bf(v2 - bf2f(hb));
          } else {
            Vf[idx] = v;
          }
        }
      }
    }
  }
}

// ------------------------------------------------------------ V transpose ---
// Vf [h][n][c] f32  ->  Vth [h][c][n] bf16 (hi only; PV is plain-bf16)
__global__ void k_vtrans(const float* __restrict__ Vf, u16* __restrict__ Vth){
  __shared__ float tile[64][65];
  int h = blockIdx.y, nt = blockIdx.x;
  int t = threadIdx.x;
  {
    int r = t >> 2, c0 = (t & 3) * 16;
    const float* src = Vf + ((size_t)h * NTOK + nt*64 + r) * 64 + c0;
#pragma unroll
    for (int j = 0; j < 4; ++j){
      f4v v = *(const f4v*)(src + j*4);
      tile[r][c0+j*4+0] = v[0]; tile[r][c0+j*4+1] = v[1];
      tile[r][c0+j*4+2] = v[2]; tile[r][c0+j*4+3] = v[3];
    }
  }
  __syncthreads();
  {
    int c = t >> 2, b = (t & 3) * 16;
    us8 o0, o1;
#pragma unroll
    for (int i = 0; i < 16; ++i){
      u16 bv = f2bf(tile[b + i][c]);
      if (i < 8) o0[i] = bv; else o1[i-8] = bv;
    }
    u16* dst = Vth + ((size_t)h * 64 + c) * NTOK + nt*64 + b;
    *(us8*)(dst)     = o0;
    *(us8*)(dst + 8) = o1;
  }
}

// --------------------------------------------------------- rel-pos einsums ---
__global__ void k_relh(const u16* __restrict__ Qh, const u16* __restrict__ Ql,
                       const float* __restrict__ rp, float* __restrict__ R){
  __shared__ float qs[64][68];
  __shared__ float rs[64][68];
  int h = blockIdx.y, qh = blockIdx.x;
  int t = threadIdx.x;
  {
    int r = t >> 2, c0 = (t & 3) * 16;
    size_t qb = ((size_t)h * NTOK + qh*64 + r) * 64 + c0;
#pragma unroll
    for (int j = 0; j < 2; ++j){
      us8 vh = *(const us8*)(Qh + qb + j*8);
      us8 vl = *(const us8*)(Ql + qb + j*8);
#pragma unroll
      for (int e = 0; e < 8; ++e)
        qs[r][c0 + j*8 + e] = bf2f(vh[e]) + bf2f(vl[e]);
    }
    const float* pr = rp + (size_t)(qh - r + 63) * 64 + c0;
#pragma unroll
    for (int j = 0; j < 4; ++j){
      f4v v = *(const f4v*)(pr + j*4);
      rs[r][c0+j*4+0]=v[0]; rs[r][c0+j*4+1]=v[1];
      rs[r][c0+j*4+2]=v[2]; rs[r][c0+j*4+3]=v[3];
    }
  }
  __syncthreads();
  int qw = t >> 2, k0 = t & 3;
  float acc[16] = {};
  for (int c = 0; c < 64; c += 4){
    f4v qv = *(const f4v*)(&qs[qw][c]);
#pragma unroll
    for (int i = 0; i < 16; ++i){
      f4v rv = *(const f4v*)(&rs[k0 + 4*i][c]);
      acc[i] += qv[0]*rv[0] + qv[1]*rv[1] + qv[2]*rv[2] + qv[3]*rv[3];
    }
  }
  float* o = R + ((size_t)h * NTOK + qh*64 + qw) * 64;
#pragma unroll
  for (int i = 0; i < 16; ++i) o[k0 + 4*i] = acc[i] * LOG2E_F;
}

__global__ void k_relw(const u16* __restrict__ Qh, const u16* __restrict__ Ql,
                       const float* __restrict__ rp, float* __restrict__ R){
  __shared__ float qs[64][68];   // [qh][c]
  __shared__ float rs[64][68];   // [kw][c]
  int h = blockIdx.y, qw = blockIdx.x;
  int t = threadIdx.x;
  {
    int r = t >> 2, c0 = (t & 3) * 16;
    size_t qb = ((size_t)h * NTOK + r*64 + qw) * 64 + c0;
#pragma unroll
    for (int j = 0; j < 2; ++j){
      us8 vh = *(const us8*)(Qh + qb + j*8);
      us8 vl = *(const us8*)(Ql + qb + j*8);
#pragma unroll
      for (int e = 0; e < 8; ++e)
        qs[r][c0 + j*8 + e] = bf2f(vh[e]) + bf2f(vl[e]);
    }
    const float* pr = rp + (size_t)(qw - r + 63) * 64 + c0;
#pragma unroll
    for (int j = 0; j < 4; ++j){
      f4v v = *(const f4v*)(pr + j*4);
      rs[r][c0+j*4+0]=v[0]; rs[r][c0+j*4+1]=v[1];
      rs[r][c0+j*4+2]=v[2]; rs[r][c0+j*4+3]=v[3];
    }
  }
  __syncthreads();
  int qh = t >> 2, k0 = t & 3;
  float acc[16] = {};
  for (int c = 0; c < 64; c += 4){
    f4v qv = *(const f4v*)(&qs[qh][c]);
#pragma unroll
    for (int i = 0; i < 16; ++i){
      f4v rv = *(const f4v*)(&rs[k0 + 4*i][c]);
      acc[i] += qv[0]*rv[0] + qv[1]*rv[1] + qv[2]*rv[2] + qv[3]*rv[3];
    }
  }
  float* o = R + ((size_t)h * NTOK + qh*64 + qw) * 64;
#pragma unroll
  for (int i = 0; i < 16; ++i) o[k0 + 4*i] = acc[i] * LOG2E_F;
}

// --------------------------------------------------------- flash attention ---
// grid (64 q-tiles, 12 heads), 4 waves x 16 q-rows. KV tile = 64.
// SWAPPED operands: S^T = mfma(K, Q); softmax state scalar per lane.
// 2-phase double-buffered K/V staging with counted vmcnt(6).
// LDS: buf0 @0 / buf1 @24576, each Kh[8K]|Kl[8K]|Vt[8K] (xor ((row&7)<<4));
//      P @49152 + wid*2304 (stride 144); Rh tile @58368 [64 q][272B pad].
__global__ __launch_bounds__(256)
void k_attn(const u16* __restrict__ Qh, const u16* __restrict__ Ql,
            const u16* __restrict__ Kh, const u16* __restrict__ Kl,
            const u16* __restrict__ Vth,
            const float* __restrict__ Rh, const float* __restrict__ Rw,
            u16* __restrict__ Oh, u16* __restrict__ Ol)
{
  constexpr int BUF1 = 24576, POFF = 49152, RHOFF = 58368;
  __shared__ __align__(16) unsigned char sm[75776];
  const int t = threadIdx.x;
  const int lane = t & 63, wid = t >> 6;
  const int l15 = lane & 15, g = lane >> 4;
  const int h = blockIdx.y;
  const int qrow0 = blockIdx.x * 64 + wid * 16;

  // staging pointers (xor-swizzled source, linear LDS dest)
  const char* kGh[2]; const char* kGl[2]; const char* vG[2];
#pragma unroll
  for (int ch = 0; ch < 2; ++ch){
    int p = ch * 4096 + t * 16;
    int row = p >> 7;
    int cb  = (p & 127) ^ ((row & 7) << 4);
    kGh[ch] = (const char*)Kh + ((size_t)h * NTOK + row) * 128 + cb;
    kGl[ch] = (const char*)Kl + ((size_t)h * NTOK + row) * 128 + cb;
    vG[ch]  = (const char*)Vth + ((size_t)h * 64 + row) * (NTOK*2) + cb;
  }

  // Rh tile -> LDS (reg round-trip: per-lane dest needs padded stride)
  {
    const char* rhg = (const char*)(Rh + ((size_t)h * NTOK + blockIdx.x * 64) * 64);
#pragma unroll
    for (int s2 = 0; s2 < 4; ++s2){
      int off = s2*4096 + t*16;
      f4v v = *(const f4v*)(rhg + off);
      *(f4v*)(sm + RHOFF + (off >> 8) * 272 + (off & 255)) = v;
    }
  }
  asm volatile("s_waitcnt lgkmcnt(0)" ::: "memory");  // publish at first barrier

  // Q fragments (B-operand; row = q = l15, d = g*8+e), held all kernel
  const size_t qoff = ((size_t)h * NTOK + qrow0 + l15) * 64 + g * 8;
  s8v qh0 = *(const s8v*)(Qh + qoff);
  s8v qh1 = *(const s8v*)(Qh + qoff + 32);
  s8v ql0 = *(const s8v*)(Ql + qoff);
  s8v ql1 = *(const s8v*)(Ql + qoff + 32);

  // K/V LDS read bases (buffer-relative)
  const int xr  = (l15 & 7) << 4;
  const int kb0 = l15 * 128 + ((g * 16)      ^ xr);
  const int kb1 = l15 * 128 + ((g * 16 + 64) ^ xr);
  const int vb0 = 16384 + kb0;
  const int vb1 = 16384 + kb1;
  const int pbase = POFF + wid * 2304 + l15 * 144;
  const int rhrd  = RHOFF + (wid * 16 + l15) * 272;

  // rel_w hoist (iteration-invariant)
  const float* rwp = Rw + ((size_t)h * NTOK + qrow0 + l15) * 64 + 4*g;
  f4v rwv[4];
#pragma unroll
  for (int tt = 0; tt < 4; ++tt) rwv[tt] = *(const f4v*)(rwp + 16*tt);

  // prologue: stage KV-tile 0 into buf0
#pragma unroll
  for (int ch = 0; ch < 2; ++ch){
    gload_lds16(kGh[ch], sm + 0     + ch*4096 + wid*1024);
    gload_lds16(kGl[ch], sm + 8192  + ch*4096 + wid*1024);
    gload_lds16(vG[ch],  sm + 16384 + ch*4096 + wid*1024);
    kGh[ch] += 8192; kGl[ch] += 8192; vG[ch] += 128;
  }

  f4v o[4] = {};
  float m2 = -1.0e30f, ls = 0.f;

  for (int it = 0; it < 64; ++it){
    const int bb = (it & 1) * BUF1;
    if (it < 63){
      const int nb = ((it + 1) & 1) * BUF1;
#pragma unroll
      for (int ch = 0; ch < 2; ++ch){
        gload_lds16(kGh[ch], sm + nb + 0     + ch*4096 + wid*1024);
        gload_lds16(kGl[ch], sm + nb + 8192  + ch*4096 + wid*1024);
        gload_lds16(vG[ch],  sm + nb + 16384 + ch*4096 + wid*1024);
        kGh[ch] += 8192; kGl[ch] += 8192; vG[ch] += 128;
      }
      asm volatile("s_waitcnt vmcnt(6)" ::: "memory");   // tile it landed
    } else {
      asm volatile("s_waitcnt vmcnt(0)" ::: "memory");
    }
    hard_barrier();

    const float rhv = *(const float*)(sm + rhrd + it * 4);

    // S^T = K Q^T (split: hh, hl, lh). s[t][r] = S[k=16t+4g+r][q=l15]
    f4v s[4];
    __builtin_amdgcn_s_setprio(1);
#pragma unroll
    for (int tt = 0; tt < 4; ++tt){
      s8v kh_0 = *(const s8v*)(sm + bb + kb0 + tt*2048);
      s8v kh_1 = *(const s8v*)(sm + bb + kb1 + tt*2048);
      s8v kl_0 = *(const s8v*)(sm + bb + kb0 + tt*2048 + 8192);
      s8v kl_1 = *(const s8v*)(sm + bb + kb1 + tt*2048 + 8192);
      f4v a = {};
      a = MFMA16(kh_0, qh0, a);
      a = MFMA16(kh_1, qh1, a);
      a = MFMA16(kl_0, qh0, a);
      a = MFMA16(kl_1, qh1, a);
      a = MFMA16(kh_0, ql0, a);
      a = MFMA16(kh_1, ql1, a);
      s[tt] = a;
    }
    __builtin_amdgcn_s_setprio(0);

    // bias + row max (all 16 values belong to q-row l15)
    float pm = -1.0e30f;
#pragma unroll
    for (int tt = 0; tt < 4; ++tt){
#pragma unroll
      for (int r = 0; r < 4; ++r){
        s[tt][r] += rhv + rwv[tt][r];
        pm = fmaxf(pm, s[tt][r]);
      }
    }
    pm = fmaxf(pm, __shfl_xor(pm, 16, 64));
    pm = fmaxf(pm, __shfl_xor(pm, 32, 64));
    const float mn = fmaxf(m2, pm);
    const float fr = EXP2(m2 - mn);
    m2 = mn;
    float ps = 0.f;
#pragma unroll
    for (int tt = 0; tt < 4; ++tt){
#pragma unroll
      for (int r = 0; r < 4; ++r){
        float p = EXP2(s[tt][r] - m2);
        s[tt][r] = p;
        ps += p;
      }
    }
    ps += __shfl_xor(ps, 16, 64);
    ps += __shfl_xor(ps, 32, 64);
    ls = ls * fr + ps;

    // P -> LDS (wave-private region, no barrier needed)
#pragma unroll
    for (int tt = 0; tt < 4; ++tt){
      u32x2 w2;
      w2[0] = cvtpk(s[tt][0], s[tt][1]);
      w2[1] = cvtpk(s[tt][2], s[tt][3]);
      *(u32x2*)(sm + pbase + 8*g + 32*tt) = w2;
    }
    // rescale O (scalar factor: accumulator is q-row-local)
#pragma unroll
    for (int dt = 0; dt < 4; ++dt){
#pragma unroll
      for (int r = 0; r < 4; ++r) o[dt][r] *= fr;
    }
    // O^T += Vt @ P^T
    s8v pa0 = *(const s8v*)(sm + pbase + 16*g);
    s8v pa1 = *(const s8v*)(sm + pbase + 16*g + 64);
    __builtin_amdgcn_s_setprio(1);
#pragma unroll
    for (int dt = 0; dt < 4; ++dt){
      s8v v0 = *(const s8v*)(sm + bb + vb0 + dt*2048);
      s8v v1 = *(const s8v*)(sm + bb + vb1 + dt*2048);
      o[dt] = MFMA16(v0, pa0, o[dt]);
      o[dt] = MFMA16(v1, pa1, o[dt]);
    }
    __builtin_amdgcn_s_setprio(0);

    hard_barrier();   // protect buf[it&1] before restage at it+2
  }

  // epilogue: o[dt][r] = O[q = qrow0+l15][d = 16dt + 4g + r]; fused hi/lo split
  const float inv = 1.0f / ls;
  const size_t obase = (size_t)(qrow0 + l15) * DM + h*64 + 4*g;
#pragma unroll
  for (int dt = 0; dt < 4; ++dt){
    us4 hv, lv;
#pragma unroll
    for (int r = 0; r < 4; ++r){
      float v = o[dt][r] * inv;
      u16 hb = f2bf(v);
      hv[r] = hb;
      lv[r] = f2bf(v - bf2f(hb));
    }
    *(us4*)(Oh + obase + 16*dt) = hv;
    *(us4*)(Ol + obase + 16*dt) = lv;
  }
}

// ------------------------------------------------------------------- host ---
extern "C" void kernel_launch(void* const* d_in, const int* in_sizes, int n_in,
                              void* d_out, int out_size, void* d_ws, size_t ws_size,
                              hipStream_t stream){
  (void)in_sizes; (void)n_in; (void)out_size; (void)ws_size;
  const float* x      = (const float*)d_in[0];
  const float* w_qkv  = (const float*)d_in[1];
  const float* b_qkv  = (const float*)d_in[2];
  const float* w_proj = (const float*)d_in[3];
  const float* b_proj = (const float*)d_in[4];
  const float* rph    = (const float*)d_in[5];
  const float* rpw    = (const float*)d_in[6];
  float* out = (float*)d_out;

  char* w = (char*)d_ws;
  size_t off = 0;
  auto nxt = [&](size_t b) -> char* {
    char* p = w + off; off += (b + 255) & ~(size_t)255; return p;
  };
  u16*   Xh  = (u16*)  nxt((size_t)NTOK*DM*2);
  u16*   Xl  = (u16*)  nxt((size_t)NTOK*DM*2);
  u16*   Wqh = (u16*)  nxt((size_t)3*DM*DM*2);
  u16*   Wql = (u16*)  nxt((size_t)3*DM*DM*2);
  u16*   Wph = (u16*)  nxt((size_t)DM*DM*2);
  u16*   Wpl = (u16*)  nxt((size_t)DM*DM*2);
  u16*   Qh  = (u16*)  nxt((size_t)NTOK*DM*2);
  u16*   Ql  = (u16*)  nxt((size_t)NTOK*DM*2);
  u16*   Kh  = (u16*)  nxt((size_t)NTOK*DM*2);
  u16*   Kl  = (u16*)  nxt((size_t)NTOK*DM*2);
  float* Vf  = (float*)nxt((size_t)NTOK*DM*4);
  u16*   Vth = (u16*)  nxt((size_t)NTOK*DM*2);
  float* Rh  = (float*)nxt((size_t)12*NTOK*64*4);
  float* Rw  = (float*)nxt((size_t)12*NTOK*64*4);
  u16*   Oh  = Xh;                                    // X dead after G1
  u16*   Ol  = Xl;

  k_split<<<dim3(3072), dim3(256), 0, stream>>>(x,      Xh,  Xl,  NTOK*DM/4);
  k_split<<<dim3(1728), dim3(256), 0, stream>>>(w_qkv,  Wqh, Wql, 3*DM*DM/4);
  k_split<<<dim3(576),  dim3(256), 0, stream>>>(w_proj, Wph, Wpl, DM*DM/4);

  k_gemm<1><<<dim3(18, 32), dim3(256), 0, stream>>>(
      Xh, Xl, Wqh, Wql, b_qkv, DM, Qh, Ql, Kh, Kl, Vf, nullptr);

  k_vtrans<<<dim3(64, 12), dim3(256), 0, stream>>>(Vf, Vth);
  k_relh  <<<dim3(64, 12), dim3(256), 0, stream>>>(Qh, Ql, rph, Rh);
  k_relw  <<<dim3(64, 12), dim3(256), 0, stream>>>(Qh, Ql, rpw, Rw);

  k_attn<<<dim3(64, 12), dim3(256), 0, stream>>>(Qh, Ql, Kh, Kl, Vth, Rh, Rw, Oh, Ol);

  k_gemm<2><<<dim3(6, 32), dim3(256), 0, stream>>>(
      Oh, Ol, Wph, Wpl, b_proj, DM,
      nullptr, nullptr, nullptr, nullptr, nullptr, out);
}

// Round 7
// 348.119 us; speedup vs baseline: 1.3136x; 1.0730x over previous
//
#include <hip/hip_runtime.h>
#include <hip/hip_bf16.h>
#include <stdint.h>

// ---------------------------------------------------------------------------
// ImageAttention (SAM-style, decomposed rel-pos) on MI355X / gfx950.
// Split-bf16 (hi+lo) MFMA for QKV/proj GEMMs and QK^T; P@V plain bf16.
// R7: k_attn = R3 single-buffer layout (33.8KB -> 4 blocks/CU) + T14
//   async-STAGE split: loads(it+2)->regs issued right after writes(it+1),
//   in flight across the publish barrier and the whole next iteration.
//   No double buffer (R6's 75.8KB halved occupancy and regressed).
// k_gemm keeps R6's 2-phase counted-vmcnt pipeline (measured ~32us win).
// ---------------------------------------------------------------------------

typedef unsigned short u16;
typedef unsigned int   u32;
typedef __attribute__((ext_vector_type(8))) short s8v;   // 8 x bf16 (4 VGPR)
typedef __attribute__((ext_vector_type(4))) float f4v;   // MFMA acc / 16B ld
typedef __attribute__((ext_vector_type(4))) unsigned short us4;
typedef __attribute__((ext_vector_type(8))) unsigned short us8;
typedef __attribute__((ext_vector_type(2))) unsigned int u32x2;

#define DEVI static __device__ __forceinline__

constexpr int   NTOK   = 4096;
constexpr int   DM     = 768;
constexpr float LOG2E_F = 1.4426950408889634f;
constexpr float KSCALE  = 0.18033688011112042f;   // (1/8) * log2(e)

#if __has_builtin(__builtin_amdgcn_exp2f)
#define EXP2(x) __builtin_amdgcn_exp2f(x)
#else
#define EXP2(x) exp2f(x)
#endif

DEVI u16 f2bf(float x){
  u32 u = __builtin_bit_cast(u32, x);
  u32 r = (u + 0x7FFFu + ((u >> 16) & 1u)) >> 16;
  return (u16)r;
}
DEVI float bf2f(u16 h){
  u32 u = ((u32)h) << 16;
  return __builtin_bit_cast(float, u);
}
DEVI u32 cvtpk(float lo, float hi){   // dst.lo16 = bf16(lo), dst.hi16 = bf16(hi)
  u32 r;
  asm("v_cvt_pk_bf16_f32 %0, %1, %2" : "=v"(r) : "v"(lo), "v"(hi));
  return r;
}

typedef const __attribute__((address_space(1))) u32* gp1;
typedef __attribute__((address_space(3))) u32* lp3;
DEVI void gload_lds16(const void* g, void* l){
  __builtin_amdgcn_global_load_lds((gp1)g, (lp3)l, 16, 0, 0);
}

DEVI f4v MFMA16(s8v a, s8v b, f4v c){
  return __builtin_amdgcn_mfma_f32_16x16x32_bf16(a, b, c, 0, 0, 0);
}

// raw barrier with compiler fences (no vmcnt/lgkm drain!)
DEVI void hard_barrier(){
  __builtin_amdgcn_sched_barrier(0);
  asm volatile("" ::: "memory");
  __builtin_amdgcn_s_barrier();
  asm volatile("" ::: "memory");
  __builtin_amdgcn_sched_barrier(0);
}

// ------------------------------------------------------------------ split ---
__global__ void k_split(const float* __restrict__ in, u16* __restrict__ hi,
                        u16* __restrict__ lo, int n4){
  int i = blockIdx.x * blockDim.x + threadIdx.x;
  int stride = gridDim.x * blockDim.x;
  for (; i < n4; i += stride){
    f4v v = ((const f4v*)in)[i];
    us4 h, l;
#pragma unroll
    for (int j = 0; j < 4; ++j){
      u16 hb = f2bf(v[j]);
      h[j] = hb;
      l[j] = f2bf(v[j] - bf2f(hb));
    }
    ((us4*)hi)[i] = h;
    ((us4*)lo)[i] = l;
  }
}

// ------------------------------------------------------------- split GEMM ---
// C[M,N] = (Ah+Al)[M,K] @ (Bh+Bl)[N,K]^T, 128x128 tile, BK=32, 4 waves.
// Double-buffered LDS (2 x 32KB), 2-phase pipeline, counted vmcnt(8). (R6)
template<int EPI>
__global__ __launch_bounds__(256)
void k_gemm(const u16* __restrict__ Ah, const u16* __restrict__ Al,
            const u16* __restrict__ Bh, const u16* __restrict__ Bl,
            const float* __restrict__ bias, int K,
            u16* __restrict__ Qh, u16* __restrict__ Ql,
            u16* __restrict__ Kh, u16* __restrict__ Kl,
            float* __restrict__ Vf, float* __restrict__ Cout)
{
  __shared__ __align__(16) unsigned char sm[65536]; // 2 x (Ah|Al|Bh|Bl 8KB)
  const int t = threadIdx.x;
  const int lane = t & 63, wid = t >> 6;
  const int l15 = lane & 15, g = lane >> 4;
  const int wr = wid >> 1, wc = wid & 1;
  const int m0 = blockIdx.y * 128, n0 = blockIdx.x * 128;

  const char* aGh[2]; const char* aGl[2]; const char* bGh[2]; const char* bGl[2];
#pragma unroll
  for (int ch = 0; ch < 2; ++ch){
    int p = ch * 4096 + t * 16;
    int pair = p >> 7, w = p & 127;
    int u = w ^ ((pair & 7) << 4);
    int row = 2 * pair + (u >> 6);
    int cb  = u & 63;
    aGh[ch] = (const char*)Ah + (size_t)(m0 + row) * K * 2 + cb;
    aGl[ch] = (const char*)Al + (size_t)(m0 + row) * K * 2 + cb;
    bGh[ch] = (const char*)Bh + (size_t)(n0 + row) * K * 2 + cb;
    bGl[ch] = (const char*)Bl + (size_t)(n0 + row) * K * 2 + cb;
  }
  const int axor = ((l15 & 1) * 64 + g * 16) ^ (((l15 >> 1) & 7) << 4);
  const int abase = (wr * 32 + (l15 >> 1)) * 128 + axor;
  const int bbase = 16384 + (wc * 32 + (l15 >> 1)) * 128 + axor;

  // prologue: stage K-step 0 into buffer 0
#pragma unroll
  for (int ch = 0; ch < 2; ++ch){
    gload_lds16(aGh[ch], sm + 0     + ch*4096 + wid*1024);
    gload_lds16(aGl[ch], sm + 8192  + ch*4096 + wid*1024);
    gload_lds16(bGh[ch], sm + 16384 + ch*4096 + wid*1024);
    gload_lds16(bGl[ch], sm + 24576 + ch*4096 + wid*1024);
    aGh[ch] += 64; aGl[ch] += 64; bGh[ch] += 64; bGl[ch] += 64;
  }

  f4v acc[4][4] = {};
  const int KSTEPS = K >> 5;
  for (int kt = 0; kt < KSTEPS; ++kt){
    const int bb = (kt & 1) * 32768;
    if (kt + 1 < KSTEPS){
      const int nb = ((kt + 1) & 1) * 32768;
#pragma unroll
      for (int ch = 0; ch < 2; ++ch){
        gload_lds16(aGh[ch], sm + nb + 0     + ch*4096 + wid*1024);
        gload_lds16(aGl[ch], sm + nb + 8192  + ch*4096 + wid*1024);
        gload_lds16(bGh[ch], sm + nb + 16384 + ch*4096 + wid*1024);
        gload_lds16(bGl[ch], sm + nb + 24576 + ch*4096 + wid*1024);
        aGh[ch] += 64; aGl[ch] += 64; bGh[ch] += 64; bGl[ch] += 64;
      }
      asm volatile("s_waitcnt vmcnt(8)" ::: "memory");   // step kt landed
    } else {
      asm volatile("s_waitcnt vmcnt(0)" ::: "memory");
    }
    hard_barrier();

    s8v af[4][2];
#pragma unroll
    for (int mi = 0; mi < 4; ++mi){
      af[mi][0] = *(const s8v*)(sm + bb + abase + mi*1024);
      af[mi][1] = *(const s8v*)(sm + bb + abase + mi*1024 + 8192);
    }
    __builtin_amdgcn_s_setprio(1);
#pragma unroll
    for (int ni = 0; ni < 4; ++ni){
      s8v bh = *(const s8v*)(sm + bb + bbase + ni*1024);
      s8v bl = *(const s8v*)(sm + bb + bbase + ni*1024 + 8192);
#pragma unroll
      for (int mi = 0; mi < 4; ++mi){
        acc[mi][ni] = MFMA16(af[mi][0], bh, acc[mi][ni]);
        acc[mi][ni] = MFMA16(af[mi][0], bl, acc[mi][ni]);
        acc[mi][ni] = MFMA16(af[mi][1], bh, acc[mi][ni]);
      }
    }
    __builtin_amdgcn_s_setprio(0);
    hard_barrier();   // protect buf[kt&1] before restage at kt+2
  }

  if (EPI == 2){
#pragma unroll
    for (int ni = 0; ni < 4; ++ni){
      int col = n0 + wc*64 + ni*16 + l15;
      float bq = bias[col];
#pragma unroll
      for (int mi = 0; mi < 4; ++mi){
        int rw0 = m0 + wr*64 + mi*16 + g*4;
#pragma unroll
        for (int r = 0; r < 4; ++r)
          Cout[(size_t)(rw0 + r) * DM + col] = acc[mi][ni][r] + bq;
      }
    }
  } else {
#pragma unroll
    for (int ni = 0; ni < 4; ++ni){
      int colb = n0 + wc*64 + ni*16;        // tile never straddles 768/64 edges
      float bq = bias[colb + l15];
      int which = colb / DM;
      int rem   = colb % DM;
      int head  = rem >> 6;
      int c     = (rem & 63) + l15;
#pragma unroll
      for (int mi = 0; mi < 4; ++mi){
        int n = m0 + wr*64 + mi*16 + g*4;
#pragma unroll
        for (int r = 0; r < 4; ++r){
          float v = acc[mi][ni][r] + bq;
          size_t idx = ((size_t)head * NTOK + (n + r)) * 64 + c;
          if (which == 0){
            u16 hb = f2bf(v);
            Qh[idx] = hb; Ql[idx] = f2bf(v - bf2f(hb));
          } else if (which == 1){
            float v2 = v * KSCALE;            // fold softmax scale * log2(e)
            u16 hb = f2bf(v2);
            Kh[idx] = hb; Kl[idx] = f2bf(v2 - bf2f(hb));
          } else {
            Vf[idx] = v;
          }
        }
      }
    }
  }
}

// ------------------------------------------------------------ V transpose ---
// Vf [h][n][c] f32  ->  Vth [h][c][n] bf16 (hi only; PV is plain-bf16)
__global__ void k_vtrans(const float* __restrict__ Vf, u16* __restrict__ Vth){
  __shared__ float tile[64][65];
  int h = blockIdx.y, nt = blockIdx.x;
  int t = threadIdx.x;
  {
    int r = t >> 2, c0 = (t & 3) * 16;
    const float* src = Vf + ((size_t)h * NTOK + nt*64 + r) * 64 + c0;
#pragma unroll
    for (int j = 0; j < 4; ++j){
      f4v v = *(const f4v*)(src + j*4);
      tile[r][c0+j*4+0] = v[0]; tile[r][c0+j*4+1] = v[1];
      tile[r][c0+j*4+2] = v[2]; tile[r][c0+j*4+3] = v[3];
    }
  }
  __syncthreads();
  {
    int c = t >> 2, b = (t & 3) * 16;
    us8 o0, o1;
#pragma unroll
    for (int i = 0; i < 16; ++i){
      u16 bv = f2bf(tile[b + i][c]);
      if (i < 8) o0[i] = bv; else o1[i-8] = bv;
    }
    u16* dst = Vth + ((size_t)h * 64 + c) * NTOK + nt*64 + b;
    *(us8*)(dst)     = o0;
    *(us8*)(dst + 8) = o1;
  }
}

// --------------------------------------------------------- rel-pos einsums ---
__global__ void k_relh(const u16* __restrict__ Qh, const u16* __restrict__ Ql,
                       const float* __restrict__ rp, float* __restrict__ R){
  __shared__ float qs[64][68];
  __shared__ float rs[64][68];
  int h = blockIdx.y, qh = blockIdx.x;
  int t = threadIdx.x;
  {
    int r = t >> 2, c0 = (t & 3) * 16;
    size_t qb = ((size_t)h * NTOK + qh*64 + r) * 64 + c0;
#pragma unroll
    for (int j = 0; j < 2; ++j){
      us8 vh = *(const us8*)(Qh + qb + j*8);
      us8 vl = *(const us8*)(Ql + qb + j*8);
#pragma unroll
      for (int e = 0; e < 8; ++e)
        qs[r][c0 + j*8 + e] = bf2f(vh[e]) + bf2f(vl[e]);
    }
    const float* pr = rp + (size_t)(qh - r + 63) * 64 + c0;
#pragma unroll
    for (int j = 0; j < 4; ++j){
      f4v v = *(const f4v*)(pr + j*4);
      rs[r][c0+j*4+0]=v[0]; rs[r][c0+j*4+1]=v[1];
      rs[r][c0+j*4+2]=v[2]; rs[r][c0+j*4+3]=v[3];
    }
  }
  __syncthreads();
  int qw = t >> 2, k0 = t & 3;
  float acc[16] = {};
  for (int c = 0; c < 64; c += 4){
    f4v qv = *(const f4v*)(&qs[qw][c]);
#pragma unroll
    for (int i = 0; i < 16; ++i){
      f4v rv = *(const f4v*)(&rs[k0 + 4*i][c]);
      acc[i] += qv[0]*rv[0] + qv[1]*rv[1] + qv[2]*rv[2] + qv[3]*rv[3];
    }
  }
  float* o = R + ((size_t)h * NTOK + qh*64 + qw) * 64;
#pragma unroll
  for (int i = 0; i < 16; ++i) o[k0 + 4*i] = acc[i] * LOG2E_F;
}

__global__ void k_relw(const u16* __restrict__ Qh, const u16* __restrict__ Ql,
                       const float* __restrict__ rp, float* __restrict__ R){
  __shared__ float qs[64][68];   // [qh][c]
  __shared__ float rs[64][68];   // [kw][c]
  int h = blockIdx.y, qw = blockIdx.x;
  int t = threadIdx.x;
  {
    int r = t >> 2, c0 = (t & 3) * 16;
    size_t qb = ((size_t)h * NTOK + r*64 + qw) * 64 + c0;
#pragma unroll
    for (int j = 0; j < 2; ++j){
      us8 vh = *(const us8*)(Qh + qb + j*8);
      us8 vl = *(const us8*)(Ql + qb + j*8);
#pragma unroll
      for (int e = 0; e < 8; ++e)
        qs[r][c0 + j*8 + e] = bf2f(vh[e]) + bf2f(vl[e]);
    }
    const float* pr = rp + (size_t)(qw - r + 63) * 64 + c0;
#pragma unroll
    for (int j = 0; j < 4; ++j){
      f4v v = *(const f4v*)(pr + j*4);
      rs[r][c0+j*4+0]=v[0]; rs[r][c0+j*4+1]=v[1];
      rs[r][c0+j*4+2]=v[2]; rs[r][c0+j*4+3]=v[3];
    }
  }
  __syncthreads();
  int qh = t >> 2, k0 = t & 3;
  float acc[16] = {};
  for (int c = 0; c < 64; c += 4){
    f4v qv = *(const f4v*)(&qs[qh][c]);
#pragma unroll
    for (int i = 0; i < 16; ++i){
      f4v rv = *(const f4v*)(&rs[k0 + 4*i][c]);
      acc[i] += qv[0]*rv[0] + qv[1]*rv[1] + qv[2]*rv[2] + qv[3]*rv[3];
    }
  }
  float* o = R + ((size_t)h * NTOK + qh*64 + qw) * 64;
#pragma unroll
  for (int i = 0; i < 16; ++i) o[k0 + 4*i] = acc[i] * LOG2E_F;
}

// --------------------------------------------------------- flash attention ---
// grid (64 q-tiles, 12 heads), 4 waves x 16 q-rows. KV tile = 64.
// SWAPPED operands: S^T = mfma(K, Q); softmax state scalar per lane.
// T14 async-STAGE split, SINGLE buffer (33.8KB -> 4 blocks/CU):
//   prologue: load(0)->regs; write(0); load(1)
//   iter it:  QKT(it); softmax; PV(it); barrierA;
//             write(it+1) from regs; load(it+2); lgkmcnt(0); barrierB
// Loads are in flight across barrierB + the entire next iteration.
// LDS: Kh[8K]@0, Kl@8192, Vt@16384 (xor ((row&7)<<4)), P@24576+wid*2304.
__global__ __launch_bounds__(256)
void k_attn(const u16* __restrict__ Qh, const u16* __restrict__ Ql,
            const u16* __restrict__ Kh, const u16* __restrict__ Kl,
            const u16* __restrict__ Vth,
            const float* __restrict__ Rh, const float* __restrict__ Rw,
            u16* __restrict__ Oh, u16* __restrict__ Ol)
{
  __shared__ __align__(16) unsigned char sm[33792];
  const int t = threadIdx.x;
  const int lane = t & 63, wid = t >> 6;
  const int l15 = lane & 15, g = lane >> 4;
  const int h = blockIdx.y;
  const int qrow0 = blockIdx.x * 64 + wid * 16;

  // staging pointers (xor-swizzled source, linear LDS dest = ch*4096 + t*16)
  const char* kGh[2]; const char* kGl[2]; const char* vG[2];
#pragma unroll
  for (int ch = 0; ch < 2; ++ch){
    int p = ch * 4096 + t * 16;
    int row = p >> 7;
    int cb  = (p & 127) ^ ((row & 7) << 4);
    kGh[ch] = (const char*)Kh + ((size_t)h * NTOK + row) * 128 + cb;
    kGl[ch] = (const char*)Kl + ((size_t)h * NTOK + row) * 128 + cb;
    vG[ch]  = (const char*)Vth + ((size_t)h * 64 + row) * (NTOK*2) + cb;
  }

  // Q fragments (B-operand; row = q = l15, d = g*8+e), held all kernel
  const size_t qoff = ((size_t)h * NTOK + qrow0 + l15) * 64 + g * 8;
  s8v qh0 = *(const s8v*)(Qh + qoff);
  s8v qh1 = *(const s8v*)(Qh + qoff + 32);
  s8v ql0 = *(const s8v*)(Ql + qoff);
  s8v ql1 = *(const s8v*)(Ql + qoff + 32);

  // K/V LDS read bases
  const int xr  = (l15 & 7) << 4;
  const int kb0 = l15 * 128 + ((g * 16)      ^ xr);
  const int kb1 = l15 * 128 + ((g * 16 + 64) ^ xr);
  const int vb0 = 16384 + kb0;
  const int vb1 = 16384 + kb1;
  const int pbase = 24576 + wid * 2304 + l15 * 144;

  // rel_w hoist (iteration-invariant); rel_h read per-iter from global (L2/L3)
  const float* rwp = Rw + ((size_t)h * NTOK + qrow0 + l15) * 64 + 4*g;
  f4v rwv[4];
#pragma unroll
  for (int tt = 0; tt < 4; ++tt) rwv[tt] = *(const f4v*)(rwp + 16*tt);
  const float* rhp = Rh + ((size_t)h * NTOK + qrow0 + l15) * 64;

  // T14 reg-staged tile: 6 x 16B per thread
  f4v st[6];
  auto do_loads = [&](){
    st[0] = *(const f4v*)kGh[0]; st[1] = *(const f4v*)kGh[1];
    st[2] = *(const f4v*)kGl[0]; st[3] = *(const f4v*)kGl[1];
    st[4] = *(const f4v*)vG[0];  st[5] = *(const f4v*)vG[1];
    kGh[0] += 8192; kGh[1] += 8192;
    kGl[0] += 8192; kGl[1] += 8192;
    vG[0]  += 128;  vG[1]  += 128;
  };
  auto do_writes = [&](){
    *(f4v*)(sm + 0     +    0 + t*16) = st[0];
    *(f4v*)(sm + 0     + 4096 + t*16) = st[1];
    *(f4v*)(sm + 8192  +    0 + t*16) = st[2];
    *(f4v*)(sm + 8192  + 4096 + t*16) = st[3];
    *(f4v*)(sm + 16384 +    0 + t*16) = st[4];
    *(f4v*)(sm + 16384 + 4096 + t*16) = st[5];
  };

  // prologue: tile 0 -> LDS; tile 1 loads in flight
  do_loads();
  do_writes();
  do_loads();
  asm volatile("s_waitcnt lgkmcnt(0)" ::: "memory");
  hard_barrier();

  f4v o[4] = {};
  float m2 = -1.0e30f, ls = 0.f;

  for (int it = 0; it < 64; ++it){
    const float rhv = rhp[it];   // rel_h: scalar per lane per iteration

    // S^T = K Q^T (split: hh, hl, lh). s[t][r] = S[k=16t+4g+r][q=l15]
    f4v s[4];
    __builtin_amdgcn_s_setprio(1);
#pragma unroll
    for (int tt = 0; tt < 4; ++tt){
      s8v kh_0 = *(const s8v*)(sm + kb0 + tt*2048);
      s8v kh_1 = *(const s8v*)(sm + kb1 + tt*2048);
      s8v kl_0 = *(const s8v*)(sm + kb0 + tt*2048 + 8192);
      s8v kl_1 = *(const s8v*)(sm + kb1 + tt*2048 + 8192);
      f4v a = {};
      a = MFMA16(kh_0, qh0, a);
      a = MFMA16(kh_1, qh1, a);
      a = MFMA16(kl_0, qh0, a);
      a = MFMA16(kl_1, qh1, a);
      a = MFMA16(kh_0, ql0, a);
      a = MFMA16(kh_1, ql1, a);
      s[tt] = a;
    }
    __builtin_amdgcn_s_setprio(0);

    // bias + row max (all 16 values belong to q-row l15)
    float pm = -1.0e30f;
#pragma unroll
    for (int tt = 0; tt < 4; ++tt){
#pragma unroll
      for (int r = 0; r < 4; ++r){
        s[tt][r] += rhv + rwv[tt][r];
        pm = fmaxf(pm, s[tt][r]);
      }
    }
    pm = fmaxf(pm, __shfl_xor(pm, 16, 64));
    pm = fmaxf(pm, __shfl_xor(pm, 32, 64));
    const float mn = fmaxf(m2, pm);
    const float fr = EXP2(m2 - mn);
    m2 = mn;
    float ps = 0.f;
#pragma unroll
    for (int tt = 0; tt < 4; ++tt){
#pragma unroll
      for (int r = 0; r < 4; ++r){
        float p = EXP2(s[tt][r] - m2);
        s[tt][r] = p;
        ps += p;
      }
    }
    ps += __shfl_xor(ps, 16, 64);
    ps += __shfl_xor(ps, 32, 64);
    ls = ls * fr + ps;

    // P -> LDS (wave-private region, no barrier needed)
#pragma unroll
    for (int tt = 0; tt < 4; ++tt){
      u32x2 w2;
      w2[0] = cvtpk(s[tt][0], s[tt][1]);
      w2[1] = cvtpk(s[tt][2], s[tt][3]);
      *(u32x2*)(sm + pbase + 8*g + 32*tt) = w2;
    }
    // rescale O (scalar factor: accumulator is q-row-local)
#pragma unroll
    for (int dt = 0; dt < 4; ++dt){
#pragma unroll
      for (int r = 0; r < 4; ++r) o[dt][r] *= fr;
    }
    // O^T += Vt @ P^T
    s8v pa0 = *(const s8v*)(sm + pbase + 16*g);
    s8v pa1 = *(const s8v*)(sm + pbase + 16*g + 64);
    __builtin_amdgcn_s_setprio(1);
#pragma unroll
    for (int dt = 0; dt < 4; ++dt){
      s8v v0 = *(const s8v*)(sm + vb0 + dt*2048);
      s8v v1 = *(const s8v*)(sm + vb1 + dt*2048);
      o[dt] = MFMA16(v0, pa0, o[dt]);
      o[dt] = MFMA16(v1, pa1, o[dt]);
    }
    __builtin_amdgcn_s_setprio(0);

    hard_barrier();          // A: all waves done reading tile it
    if (it < 63){
      do_writes();           // tile it+1 -> LDS (compiler waits the loads)
      if (it < 62) do_loads();   // tile it+2 -> regs, in flight across B
    }
    asm volatile("s_waitcnt lgkmcnt(0)" ::: "memory");
    hard_barrier();          // B: writes visible to all waves
  }

  // epilogue: o[dt][r] = O[q = qrow0+l15][d = 16dt + 4g + r]; fused hi/lo split
  const float inv = 1.0f / ls;
  const size_t obase = (size_t)(qrow0 + l15) * DM + h*64 + 4*g;
#pragma unroll
  for (int dt = 0; dt < 4; ++dt){
    us4 hv, lv;
#pragma unroll
    for (int r = 0; r < 4; ++r){
      float v = o[dt][r] * inv;
      u16 hb = f2bf(v);
      hv[r] = hb;
      lv[r] = f2bf(v - bf2f(hb));
    }
    *(us4*)(Oh + obase + 16*dt) = hv;
    *(us4*)(Ol + obase + 16*dt) = lv;
  }
}

// ------------------------------------------------------------------- host ---
extern "C" void kernel_launch(void* const* d_in, const int* in_sizes, int n_in,
                              void* d_out, int out_size, void* d_ws, size_t ws_size,
                              hipStream_t stream){
  (void)in_sizes; (void)n_in; (void)out_size; (void)ws_size;
  const float* x      = (const float*)d_in[0];
  const float* w_qkv  = (const float*)d_in[1];
  const float* b_qkv  = (const float*)d_in[2];
  const float* w_proj = (const float*)d_in[3];
  const float* b_proj = (const float*)d_in[4];
  const float* rph    = (const float*)d_in[5];
  const float* rpw    = (const float*)d_in[6];
  float* out = (float*)d_out;

  char* w = (char*)d_ws;
  size_t off = 0;
  auto nxt = [&](size_t b) -> char* {
    char* p = w + off; off += (b + 255) & ~(size_t)255; return p;
  };
  u16*   Xh  = (u16*)  nxt((size_t)NTOK*DM*2);
  u16*   Xl  = (u16*)  nxt((size_t)NTOK*DM*2);
  u16*   Wqh = (u16*)  nxt((size_t)3*DM*DM*2);
  u16*   Wql = (u16*)  nxt((size_t)3*DM*DM*2);
  u16*   Wph = (u16*)  nxt((size_t)DM*DM*2);
  u16*   Wpl = (u16*)  nxt((size_t)DM*DM*2);
  u16*   Qh  = (u16*)  nxt((size_t)NTOK*DM*2);
  u16*   Ql  = (u16*)  nxt((size_t)NTOK*DM*2);
  u16*   Kh  = (u16*)  nxt((size_t)NTOK*DM*2);
  u16*   Kl  = (u16*)  nxt((size_t)NTOK*DM*2);
  float* Vf  = (float*)nxt((size_t)NTOK*DM*4);
  u16*   Vth = (u16*)  nxt((size_t)NTOK*DM*2);
  float* Rh  = (float*)nxt((size_t)12*NTOK*64*4);
  float* Rw  = (float*)nxt((size_t)12*NTOK*64*4);
  u16*   Oh  = Xh;                                    // X dead after G1
  u16*   Ol  = Xl;

  k_split<<<dim3(3072), dim3(256), 0, stream>>>(x,      Xh,  Xl,  NTOK*DM/4);
  k_split<<<dim3(1728), dim3(256), 0, stream>>>(w_qkv,  Wqh, Wql, 3*DM*DM/4);
  k_split<<<dim3(576),  dim3(256), 0, stream>>>(w_proj, Wph, Wpl, DM*DM/4);

  k_gemm<1><<<dim3(18, 32), dim3(256), 0, stream>>>(
      Xh, Xl, Wqh, Wql, b_qkv, DM, Qh, Ql, Kh, Kl, Vf, nullptr);

  k_vtrans<<<dim3(64, 12), dim3(256), 0, stream>>>(Vf, Vth);
  k_relh  <<<dim3(64, 12), dim3(256), 0, stream>>>(Qh, Ql, rph, Rh);
  k_relw  <<<dim3(64, 12), dim3(256), 0, stream>>>(Qh, Ql, rpw, Rw);

  k_attn<<<dim3(64, 12), dim3(256), 0, stream>>>(Qh, Ql, Kh, Kl, Vth, Rh, Rw, Oh, Ol);

  k_gemm<2><<<dim3(6, 32), dim3(256), 0, stream>>>(
      Oh, Ol, Wph, Wpl, b_proj, DM,
      nullptr, nullptr, nullptr, nullptr, nullptr, out);
}